// Round 8
// baseline (100.729 us; speedup 1.0000x reference)
//
#include <hip/hip_runtime.h>
#include <math.h>

// Problem constants
#define K_CODES 1024
#define C_DIM   128
#define HW      4096          // 64*64
#define CHW     (C_DIM*HW)    // per-batch stride in x
#define N_POS   65536         // 16*64*64
#define Q_ELEMS 8388608       // 16*128*64*64

// ws layout (byte offsets).
#define WS_S    0             // float: sum of sqrt(d2min)
#define WS_C2   256           // float[1024]: ||c_k||^2
#define WS_IDX  8192          // int[65536]: final argmin index per position

// d_out scratch (overwritten later; stream-ordered, safe):
//   offset 0: bf16 codebook (256 KB), row k at k*256B, granule-col j holds
//   channels of granule (j ^ (k&7)) -> linear global_load_lds staging +
//   conflict-free swizzled ds_read_b128 A-frags. This region == q's
//   (b=0, c<16) slice, so b=0 blocks skip the fused q-store (write_q0
//   covers batch 0 after vq completes).

typedef __attribute__((ext_vector_type(8))) short short8;   // 8 bf16 (4 VGPRs)
typedef __attribute__((ext_vector_type(4))) float f32x4;    // MFMA acc

__device__ __forceinline__ unsigned short f2bf(float f) {   // fp32 -> bf16 RNE
    unsigned u = __float_as_uint(f);
    u += 0x7FFFu + ((u >> 16) & 1u);
    return (unsigned short)(u >> 16);
}

// async global->LDS, 16B per lane; LDS dst = wave-uniform base (+lane*16 by HW)
__device__ __forceinline__ void gll16(const void* g, void* l) {
    __builtin_amdgcn_global_load_lds(
        (const __attribute__((address_space(1))) void*)g,
        (__attribute__((address_space(3))) void*)l, 16, 0, 0);
}

// ---------------------------------------------------------------------------
// Kernel 1: prep. Block k (64 lanes): row norm, bf16 conversion into the
// COLUMN-SWIZZLED global layout, S zeroing. (unchanged)
// ---------------------------------------------------------------------------
__global__ void prep_kernel(const float* __restrict__ cb, float* __restrict__ ws,
                            unsigned short* __restrict__ cbbf) {
    __shared__ __align__(16) unsigned short srow[128];
    int k = blockIdx.x;
    int l = threadIdx.x;                       // 64 lanes = 1 wave
    if (k == 0 && l == 0) *(float*)((char*)ws + WS_S) = 0.f;
    float v1 = cb[k * C_DIM + l];
    float v2 = cb[k * C_DIM + 64 + l];
    int c1 = l, c2 = 64 + l;
    srow[(((c1 >> 3) ^ (k & 7)) << 3) | (c1 & 7)] = f2bf(v1);
    srow[(((c2 >> 3) ^ (k & 7)) << 3) | (c2 & 7)] = f2bf(v2);
    float ss = v1 * v1 + v2 * v2;
    #pragma unroll
    for (int off = 32; off > 0; off >>= 1) ss += __shfl_down(ss, off);
    if (l == 0) ((float*)((char*)ws + WS_C2))[k] = ss;
    __syncthreads();
    if (l < 16) ((uint4*)cbbf)[k * 16 + l] = ((const uint4*)srow)[l];
}

// ---------------------------------------------------------------------------
// Kernel 2: fused VQ. R14 = R13's wave-private barrier-free scan with the
// staging chunk HALVED (16 codes = 4 KB/wave) -> LDS 69 -> 36.1 KB ->
// 4 BLOCKS/CU (16 waves/CU, 4/SIMD -- 2x the latency hiding; R13 evidence:
// all pipes <40%, occupancy 18% -> latency-bound). launch_bounds(256,4),
// VGPR 116 fits the 128 cap. Per chunk: stage next (4x gll16, wave-private
// dbuf, wave-local vmcnt sync), 4x ds_read_b128 swizzled A-frags, 16 MFMA
// (4pt x 4cs), 16 packed-score inserts. Totals and math byte-identical to
// R13 (top-3 of a strict total order is insert-order-independent -- proven
// absmax 0.0 across R12->R13's reorder). Merge/rescore/fused-store tail
// unchanged from R13.
// ---------------------------------------------------------------------------
__global__ __launch_bounds__(256, 4) void vq_mfma(const float* __restrict__ x,
                                                  const float* __restrict__ cb,
                                                  const unsigned short* __restrict__ cbbf,
                                                  const float* __restrict__ c2w,
                                                  int* __restrict__ idxw,
                                                  float* __restrict__ Sw,
                                                  float* __restrict__ out) {
    __shared__ __align__(16) unsigned short cbuf[2][4][2048]; // 2 x 4 x 4 KB
    __shared__ float mbuf[4][4][16][3];                       // 3 KB
    __shared__ int ibuf[64];                                  // 256 B

    const int t  = threadIdx.x;
    const int w  = t >> 6;                      // wave 0..3 = code quarter
    const int ln = t & 63;
    const int lp = ln & 15;                     // position lane (n index)
    const int q  = ln >> 4;                     // quad 0..3 (k sub-range)
    const int bid = blockIdx.x;
    const int b   = bid >> 6;                   // batch (64 blocks per image)
    const int s0  = (bid & 63) << 6;            // 64-position tile start

    // wave's quarter of the pre-swizzled bf16 codebook (64 KB)
    const char* gq = (const char*)cbbf + (w << 16);

    { // stage chunk 0 (16 codes, 4 KB) -> buf 0 NOW; hides under the x-phase
        const char* gs = gq + (ln << 4);
        char* ld = (char*)&cbuf[0][w][0];
        #pragma unroll
        for (int r = 0; r < 4; ++r) gll16(gs + r * 1024, ld + r * 1024);
    }

    // ---- x: bf16 B-frags (4 pos-tiles = all 64 positions) + norms ----
    short8 xf[4][4];
    float  r2v[4];
    {
        float ss[4];
        #pragma unroll
        for (int pt = 0; pt < 4; ++pt) {
            ss[pt] = 0.f;
            const float* xgp = x + b * CHW + s0 + pt * 16 + lp;
            #pragma unroll
            for (int cs = 0; cs < 4; ++cs) {
                union { short8 v; unsigned short u[8]; } fu;
                #pragma unroll
                for (int j = 0; j < 8; ++j) {
                    float vv = xgp[(32 * cs + 8 * q + j) * HW];
                    ss[pt] = fmaf(vv, vv, ss[pt]);
                    fu.u[j] = f2bf(vv);
                }
                xf[pt][cs] = fu.v;
            }
        }
        #pragma unroll
        for (int pt = 0; pt < 4; ++pt) {
            float s = ss[pt];
            s += __shfl_xor(s, 16);
            s += __shfl_xor(s, 32);
            r2v[pt] = -2.0f / fmaxf(sqrtf(s), 1e-12f);  // F.normalize eps
        }
    }

    const float FMAX = __uint_as_float(0x7F7FFFFFu);
    float m1[4] = {FMAX, FMAX, FMAX, FMAX};
    float m2[4] = {FMAX, FMAX, FMAX, FMAX};
    float m3[4] = {FMAX, FMAX, FMAX, FMAX};

    // chunk 0 landed (wave-local; also drains x loads, long consumed)
    asm volatile("s_waitcnt vmcnt(0)" ::: "memory");
    __builtin_amdgcn_sched_barrier(0);

    for (int i = 0; i < 16; ++i) {              // 16 chunks x 16 codes
        if (i < 15) {                            // stage next chunk (private)
            asm volatile("s_waitcnt lgkmcnt(0)" ::: "memory");
            const char* gs = gq + (i + 1) * 4096 + (ln << 4);
            char* ld = (char*)&cbuf[(i + 1) & 1][w][0];
            #pragma unroll
            for (int r = 0; r < 4; ++r) gll16(gs + r * 1024, ld + r * 1024);
        }

        const int k0 = (w << 8) + (i << 4);
        const unsigned short* cbp = &cbuf[i & 1][w][0];

        f32x4 acc[4];
        #pragma unroll
        for (int pt = 0; pt < 4; ++pt) acc[pt] = 0;

        #pragma unroll
        for (int cs = 0; cs < 4; ++cs) {
            // A[m=lp][k=32cs+8q+j]; row-within-chunk = lp, swizzled granule
            int g = lp * 16 + ((4 * cs + q) ^ (lp & 7));
            short8 ah = *(const short8*)(cbp + g * 8);
            #pragma unroll
            for (int pt = 0; pt < 4; ++pt)
                acc[pt] = __builtin_amdgcn_mfma_f32_16x16x32_bf16(
                    ah, xf[pt][cs], acc[pt], 0, 0, 0);
        }

        // ---- epilogue: 16 scores/lane (4pt x 4reg) ----
        {
            float4 c2vv = *(const float4*)(c2w + k0 + 4 * q);
            float c2a[4] = {c2vv.x, c2vv.y, c2vv.z, c2vv.w};
            const int kb0 = k0 + 4 * q;
            #pragma unroll
            for (int pt = 0; pt < 4; ++pt) {
                #pragma unroll
                for (int reg = 0; reg < 4; ++reg) {
                    float s = fmaf(r2v[pt], acc[pt][reg], c2a[reg]);
                    unsigned pb = (__float_as_uint(s) & 0xFFFFFC00u) |
                                  (unsigned)(kb0 + reg);
                    float u  = __uint_as_float(pb);
                    float t3 = __builtin_amdgcn_fmed3f(m2[pt], m3[pt], u);
                    float t2 = __builtin_amdgcn_fmed3f(m1[pt], m2[pt], u);
                    m1[pt] = fminf(m1[pt], u); m2[pt] = t2; m3[pt] = t3;
                }
            }
        }

        if (i < 15) {                            // next chunk landed (wave-local)
            asm volatile("s_waitcnt vmcnt(0)" ::: "memory");
            __builtin_amdgcn_sched_barrier(0);
        }
    }

    // ---- merge chains across the 4 quad-lanes (butterfly, all 4 pt) ----
    #pragma unroll
    for (int d = 16; d <= 32; d <<= 1) {
        #pragma unroll
        for (int pt = 0; pt < 4; ++pt) {
            float o1 = __shfl_xor(m1[pt], d), o2 = __shfl_xor(m2[pt], d),
                  o3 = __shfl_xor(m3[pt], d);
            float u, t2, t3;
            u = o1; t3 = __builtin_amdgcn_fmed3f(m2[pt], m3[pt], u);
            t2 = __builtin_amdgcn_fmed3f(m1[pt], m2[pt], u);
            m1[pt] = fminf(m1[pt], u); m2[pt] = t2; m3[pt] = t3;
            u = o2; t3 = __builtin_amdgcn_fmed3f(m2[pt], m3[pt], u);
            t2 = __builtin_amdgcn_fmed3f(m1[pt], m2[pt], u);
            m1[pt] = fminf(m1[pt], u); m2[pt] = t2; m3[pt] = t3;
            u = o3; t3 = __builtin_amdgcn_fmed3f(m2[pt], m3[pt], u);
            t2 = __builtin_amdgcn_fmed3f(m1[pt], m2[pt], u);
            m1[pt] = fminf(m1[pt], u); m2[pt] = t2; m3[pt] = t3;
        }
    }

    // publish all 4 per-quarter chains
    if (ln < 16) {
        #pragma unroll
        for (int pt = 0; pt < 4; ++pt) {
            mbuf[w][pt][lp][0] = m1[pt];
            mbuf[w][pt][lp][1] = m2[pt];
            mbuf[w][pt][lp][2] = m3[pt];
        }
    }
    __syncthreads();

    // ---- rescore: wave 0 -> positions 0-31 (pt 0,1), wave 1 -> 32-63 ----
    if (w < 2) {
        float lsum = 0.f;
        #pragma unroll
        for (int ptl = 0; ptl < 2; ++ptl) {
            const int pt = 2 * w + ptl;
            // merge the 4 quarters' chains (fixed order; unique top-3 set)
            float M1 = FMAX, M2 = FMAX, M3 = FMAX;
            #pragma unroll
            for (int ww = 0; ww < 4; ++ww)
                #pragma unroll
                for (int c = 0; c < 3; ++c) {
                    float u  = mbuf[ww][pt][lp][c];
                    float t3 = __builtin_amdgcn_fmed3f(M2, M3, u);
                    float t2 = __builtin_amdgcn_fmed3f(M1, M2, u);
                    M1 = fminf(M1, u); M2 = t2; M3 = t3;
                }
            int ks[3] = {(int)(__float_as_uint(M1) & 1023u),
                         (int)(__float_as_uint(M2) & 1023u),
                         (int)(__float_as_uint(M3) & 1023u)};

            // re-read this position's 32 channels (L1/L2-hot)
            float xr[32];
            const float* xgp = x + b * CHW + s0 + pt * 16 + lp;
            #pragma unroll
            for (int cs = 0; cs < 4; ++cs)
                #pragma unroll
                for (int j = 0; j < 8; ++j)
                    xr[cs * 8 + j] = xgp[(32 * cs + 8 * q + j) * HW];

            // exact fp32 rescore of the 3 candidates (same order as R4-R13)
            float dots[3];
            #pragma unroll
            for (int jj = 0; jj < 3; ++jj) {
                const float* crow = cb + ks[jj] * C_DIM + 8 * q;
                float p = 0.f;
                #pragma unroll
                for (int cs = 0; cs < 4; ++cs) {
                    float4 a0 = *(const float4*)(crow + 32 * cs);
                    float4 a1 = *(const float4*)(crow + 32 * cs + 4);
                    p = fmaf(xr[cs*8+0], a0.x, p); p = fmaf(xr[cs*8+1], a0.y, p);
                    p = fmaf(xr[cs*8+2], a0.z, p); p = fmaf(xr[cs*8+3], a0.w, p);
                    p = fmaf(xr[cs*8+4], a1.x, p); p = fmaf(xr[cs*8+5], a1.y, p);
                    p = fmaf(xr[cs*8+6], a1.z, p); p = fmaf(xr[cs*8+7], a1.w, p);
                }
                p += __shfl_xor(p, 16);
                p += __shfl_xor(p, 32);
                dots[jj] = p;
            }
            float sb = fmaf(r2v[pt], dots[0], c2w[ks[0]]); int kb = ks[0];
            float s2 = fmaf(r2v[pt], dots[1], c2w[ks[1]]);
            if (s2 < sb || (s2 == sb && ks[1] < kb)) { sb = s2; kb = ks[1]; }
            float s3 = fmaf(r2v[pt], dots[2], c2w[ks[2]]);
            if (s3 < sb || (s3 == sb && ks[2] < kb)) { sb = s3; kb = ks[2]; }

            if (ln < 16) {
                idxw[bid * 64 + pt * 16 + lp] = kb;
                ibuf[pt * 16 + lp] = kb;         // publish for fused store
            }
            lsum += sqrtf(fmaxf(1.0f + sb, 0.f));   // z2 == 1 after normalize
        }
        // each position counted by its 4 q-lanes -> scale 0.25
        #pragma unroll
        for (int off = 32; off > 0; off >>= 1) lsum += __shfl_down(lsum, off);
        if (ln == 0) atomicAdd(Sw, 0.25f * lsum);
    }

    // ---- fused q-store (b>0; batch 0's region aliases cbbf -> write_q0) ----
    __syncthreads();                             // ibuf visible to all waves
    if (b != 0) {
        const int row = ibuf[ln];                // position s0+ln's code
        const float4* cbr = (const float4*)cb + row * 32;
        float* ob = out + b * CHW + s0 + ln;
        #pragma unroll
        for (int c4 = w * 8; c4 < w * 8 + 8; ++c4) {   // wave w: 32 channels
            float4 v = cbr[c4];                  // 16B gather, L2-hot
            float* o = ob + (c4 * 4) * HW;
            o[0]      = v.x;                     // each store: 64 lanes x 4B
            o[HW]     = v.y;                     //  = coalesced 256B segment
            o[2 * HW] = v.z;
            o[3 * HW] = v.w;
        }
    }
}

// ---------------------------------------------------------------------------
// Kernel 3: batch-0 scatter (region was cbbf scratch during vq) + losses.
// ---------------------------------------------------------------------------
__global__ void write_q0(const float* __restrict__ cb,
                         const int* __restrict__ idxw,
                         const float* __restrict__ ws,
                         float* __restrict__ out) {
    int id = blockIdx.x * 256 + threadIdx.x;   // 131072 = 4096 * 32
    int s  = id & 4095;                        // spatial (lanes consecutive)
    int c4 = id >> 12;                         // channel quad 0..31
    int row = idxw[s];                         // batch 0 -> p == s
    float4 v = ((const float4*)cb)[row * 32 + c4];   // 16B gather, L2-hot
    float* o = out + (c4 * 4) * HW + s;        // b = 0
    o[0]      = v.x;
    o[HW]     = v.y;
    o[2 * HW] = v.z;
    o[3 * HW] = v.w;
    if (id == 0) {                             // loss finalize (after vq)
        float S = *(const float*)((const char*)ws + WS_S);
        float m = S / (float)N_POS;
        out[Q_ELEMS]     = 0.25f * m;
        out[Q_ELEMS + 1] = m;
    }
}

extern "C" void kernel_launch(void* const* d_in, const int* in_sizes, int n_in,
                              void* d_out, int out_size, void* d_ws, size_t ws_size,
                              hipStream_t stream) {
    const float* x  = (const float*)d_in[0];   // [16,128,64,64]
    const float* cb = (const float*)d_in[1];   // [1024,128]
    float* out = (float*)d_out;
    float* ws  = (float*)d_ws;

    const float* c2w = (const float*)((const char*)d_ws + WS_C2);
    int*  idxw = (int*)((char*)d_ws + WS_IDX);
    float* Sw  = (float*)((char*)d_ws + WS_S);
    unsigned short* cbbf = (unsigned short*)d_out;   // scratch in d_out

    prep_kernel<<<K_CODES, 64, 0, stream>>>(cb, ws, cbbf);
    vq_mfma    <<<N_POS / 64, 256, 0, stream>>>(x, cb, cbbf, c2w, idxw, Sw, out);
    write_q0   <<<512, 256, 0, stream>>>(cb, idxw, ws, out);
}

// Round 9
// 74.054 us; speedup vs baseline: 1.3602x; 1.3602x over previous
//
#include <hip/hip_runtime.h>
#include <math.h>

// Problem constants
#define K_CODES 1024
#define C_DIM   128
#define HW      4096          // 64*64
#define CHW     (C_DIM*HW)    // per-batch stride in x
#define N_POS   65536         // 16*64*64
#define Q_ELEMS 8388608       // 16*128*64*64

// ws layout (byte offsets).
#define WS_S    0             // float: sum of sqrt(d2min)
#define WS_C2   256           // float[1024]: ||c_k||^2
#define WS_IDX  8192          // int[65536]: final argmin index per position

// d_out scratch (overwritten later; stream-ordered, safe):
//   offset 0: bf16 codebook (256 KB), row k at k*256B, granule-col j holds
//   channels of granule (j ^ (k&7)) -> linear global_load_lds staging +
//   conflict-free swizzled ds_read_b128 A-frags. This region == q's
//   (b=0, c<16) slice, so b=0 blocks skip the fused q-store (write_q0
//   covers batch 0 after vq completes).

typedef __attribute__((ext_vector_type(8))) short short8;   // 8 bf16 (4 VGPRs)
typedef __attribute__((ext_vector_type(4))) float f32x4;    // MFMA acc

__device__ __forceinline__ unsigned short f2bf(float f) {   // fp32 -> bf16 RNE
    unsigned u = __float_as_uint(f);
    u += 0x7FFFu + ((u >> 16) & 1u);
    return (unsigned short)(u >> 16);
}

// async global->LDS, 16B per lane; LDS dst = wave-uniform base (+lane*16 by HW)
__device__ __forceinline__ void gll16(const void* g, void* l) {
    __builtin_amdgcn_global_load_lds(
        (const __attribute__((address_space(1))) void*)g,
        (__attribute__((address_space(3))) void*)l, 16, 0, 0);
}

// ---------------------------------------------------------------------------
// Kernel 1: prep. Block k (64 lanes): row norm, bf16 conversion into the
// COLUMN-SWIZZLED global layout, S zeroing. (unchanged)
// ---------------------------------------------------------------------------
__global__ void prep_kernel(const float* __restrict__ cb, float* __restrict__ ws,
                            unsigned short* __restrict__ cbbf) {
    __shared__ __align__(16) unsigned short srow[128];
    int k = blockIdx.x;
    int l = threadIdx.x;                       // 64 lanes = 1 wave
    if (k == 0 && l == 0) *(float*)((char*)ws + WS_S) = 0.f;
    float v1 = cb[k * C_DIM + l];
    float v2 = cb[k * C_DIM + 64 + l];
    int c1 = l, c2 = 64 + l;
    srow[(((c1 >> 3) ^ (k & 7)) << 3) | (c1 & 7)] = f2bf(v1);
    srow[(((c2 >> 3) ^ (k & 7)) << 3) | (c2 & 7)] = f2bf(v2);
    float ss = v1 * v1 + v2 * v2;
    #pragma unroll
    for (int off = 32; off > 0; off >>= 1) ss += __shfl_down(ss, off);
    if (l == 0) ((float*)((char*)ws + WS_C2))[k] = ss;
    __syncthreads();
    if (l < 16) ((uint4*)cbbf)[k * 16 + l] = ((const uint4*)srow)[l];
}

// ---------------------------------------------------------------------------
// Kernel 2: fused VQ. R15 = R14 (wave-private barrier-free scan, 16-code
// 4 KB chunks, 36 KB LDS -> 4 blocks/CU possible) with launch_bounds
// REVERTED to (256,2). R14's (256,4) squeezed VGPR to 64 -> ~174 MB scratch
// spills (WRITE_SIZE signature) and a 110 us disaster. (256,2) lets the
// allocator use ~116 VGPR (R13's footprint; fits the <=128 bucket), so the
// HARDWARE can still co-schedule 4 blocks/CU = 4 waves/SIMD from the LDS
// budget alone -- occupancy doubles vs R13 without spills. Math/order
// byte-identical to R13/R14 (absmax 0.0 lineage).
// ---------------------------------------------------------------------------
__global__ __launch_bounds__(256, 2) void vq_mfma(const float* __restrict__ x,
                                                  const float* __restrict__ cb,
                                                  const unsigned short* __restrict__ cbbf,
                                                  const float* __restrict__ c2w,
                                                  int* __restrict__ idxw,
                                                  float* __restrict__ Sw,
                                                  float* __restrict__ out) {
    __shared__ __align__(16) unsigned short cbuf[2][4][2048]; // 2 x 4 x 4 KB
    __shared__ float mbuf[4][4][16][3];                       // 3 KB
    __shared__ int ibuf[64];                                  // 256 B

    const int t  = threadIdx.x;
    const int w  = t >> 6;                      // wave 0..3 = code quarter
    const int ln = t & 63;
    const int lp = ln & 15;                     // position lane (n index)
    const int q  = ln >> 4;                     // quad 0..3 (k sub-range)
    const int bid = blockIdx.x;
    const int b   = bid >> 6;                   // batch (64 blocks per image)
    const int s0  = (bid & 63) << 6;            // 64-position tile start

    // wave's quarter of the pre-swizzled bf16 codebook (64 KB)
    const char* gq = (const char*)cbbf + (w << 16);

    { // stage chunk 0 (16 codes, 4 KB) -> buf 0 NOW; hides under the x-phase
        const char* gs = gq + (ln << 4);
        char* ld = (char*)&cbuf[0][w][0];
        #pragma unroll
        for (int r = 0; r < 4; ++r) gll16(gs + r * 1024, ld + r * 1024);
    }

    // ---- x: bf16 B-frags (4 pos-tiles = all 64 positions) + norms ----
    short8 xf[4][4];
    float  r2v[4];
    {
        float ss[4];
        #pragma unroll
        for (int pt = 0; pt < 4; ++pt) {
            ss[pt] = 0.f;
            const float* xgp = x + b * CHW + s0 + pt * 16 + lp;
            #pragma unroll
            for (int cs = 0; cs < 4; ++cs) {
                union { short8 v; unsigned short u[8]; } fu;
                #pragma unroll
                for (int j = 0; j < 8; ++j) {
                    float vv = xgp[(32 * cs + 8 * q + j) * HW];
                    ss[pt] = fmaf(vv, vv, ss[pt]);
                    fu.u[j] = f2bf(vv);
                }
                xf[pt][cs] = fu.v;
            }
        }
        #pragma unroll
        for (int pt = 0; pt < 4; ++pt) {
            float s = ss[pt];
            s += __shfl_xor(s, 16);
            s += __shfl_xor(s, 32);
            r2v[pt] = -2.0f / fmaxf(sqrtf(s), 1e-12f);  // F.normalize eps
        }
    }

    const float FMAX = __uint_as_float(0x7F7FFFFFu);
    float m1[4] = {FMAX, FMAX, FMAX, FMAX};
    float m2[4] = {FMAX, FMAX, FMAX, FMAX};
    float m3[4] = {FMAX, FMAX, FMAX, FMAX};

    // chunk 0 landed (wave-local; also drains x loads, long consumed)
    asm volatile("s_waitcnt vmcnt(0)" ::: "memory");
    __builtin_amdgcn_sched_barrier(0);

    for (int i = 0; i < 16; ++i) {              // 16 chunks x 16 codes
        if (i < 15) {                            // stage next chunk (private)
            asm volatile("s_waitcnt lgkmcnt(0)" ::: "memory");
            const char* gs = gq + (i + 1) * 4096 + (ln << 4);
            char* ld = (char*)&cbuf[(i + 1) & 1][w][0];
            #pragma unroll
            for (int r = 0; r < 4; ++r) gll16(gs + r * 1024, ld + r * 1024);
        }

        const int k0 = (w << 8) + (i << 4);
        const unsigned short* cbp = &cbuf[i & 1][w][0];

        f32x4 acc[4];
        #pragma unroll
        for (int pt = 0; pt < 4; ++pt) acc[pt] = 0;

        #pragma unroll
        for (int cs = 0; cs < 4; ++cs) {
            // A[m=lp][k=32cs+8q+j]; row-within-chunk = lp, swizzled granule
            int g = lp * 16 + ((4 * cs + q) ^ (lp & 7));
            short8 ah = *(const short8*)(cbp + g * 8);
            #pragma unroll
            for (int pt = 0; pt < 4; ++pt)
                acc[pt] = __builtin_amdgcn_mfma_f32_16x16x32_bf16(
                    ah, xf[pt][cs], acc[pt], 0, 0, 0);
        }

        // ---- epilogue: 16 scores/lane (4pt x 4reg) ----
        {
            float4 c2vv = *(const float4*)(c2w + k0 + 4 * q);
            float c2a[4] = {c2vv.x, c2vv.y, c2vv.z, c2vv.w};
            const int kb0 = k0 + 4 * q;
            #pragma unroll
            for (int pt = 0; pt < 4; ++pt) {
                #pragma unroll
                for (int reg = 0; reg < 4; ++reg) {
                    float s = fmaf(r2v[pt], acc[pt][reg], c2a[reg]);
                    unsigned pb = (__float_as_uint(s) & 0xFFFFFC00u) |
                                  (unsigned)(kb0 + reg);
                    float u  = __uint_as_float(pb);
                    float t3 = __builtin_amdgcn_fmed3f(m2[pt], m3[pt], u);
                    float t2 = __builtin_amdgcn_fmed3f(m1[pt], m2[pt], u);
                    m1[pt] = fminf(m1[pt], u); m2[pt] = t2; m3[pt] = t3;
                }
            }
        }

        if (i < 15) {                            // next chunk landed (wave-local)
            asm volatile("s_waitcnt vmcnt(0)" ::: "memory");
            __builtin_amdgcn_sched_barrier(0);
        }
    }

    // ---- merge chains across the 4 quad-lanes (butterfly, all 4 pt) ----
    #pragma unroll
    for (int d = 16; d <= 32; d <<= 1) {
        #pragma unroll
        for (int pt = 0; pt < 4; ++pt) {
            float o1 = __shfl_xor(m1[pt], d), o2 = __shfl_xor(m2[pt], d),
                  o3 = __shfl_xor(m3[pt], d);
            float u, t2, t3;
            u = o1; t3 = __builtin_amdgcn_fmed3f(m2[pt], m3[pt], u);
            t2 = __builtin_amdgcn_fmed3f(m1[pt], m2[pt], u);
            m1[pt] = fminf(m1[pt], u); m2[pt] = t2; m3[pt] = t3;
            u = o2; t3 = __builtin_amdgcn_fmed3f(m2[pt], m3[pt], u);
            t2 = __builtin_amdgcn_fmed3f(m1[pt], m2[pt], u);
            m1[pt] = fminf(m1[pt], u); m2[pt] = t2; m3[pt] = t3;
            u = o3; t3 = __builtin_amdgcn_fmed3f(m2[pt], m3[pt], u);
            t2 = __builtin_amdgcn_fmed3f(m1[pt], m2[pt], u);
            m1[pt] = fminf(m1[pt], u); m2[pt] = t2; m3[pt] = t3;
        }
    }

    // publish all 4 per-quarter chains
    if (ln < 16) {
        #pragma unroll
        for (int pt = 0; pt < 4; ++pt) {
            mbuf[w][pt][lp][0] = m1[pt];
            mbuf[w][pt][lp][1] = m2[pt];
            mbuf[w][pt][lp][2] = m3[pt];
        }
    }
    __syncthreads();

    // ---- rescore: wave 0 -> positions 0-31 (pt 0,1), wave 1 -> 32-63 ----
    if (w < 2) {
        float lsum = 0.f;
        #pragma unroll
        for (int ptl = 0; ptl < 2; ++ptl) {
            const int pt = 2 * w + ptl;
            // merge the 4 quarters' chains (fixed order; unique top-3 set)
            float M1 = FMAX, M2 = FMAX, M3 = FMAX;
            #pragma unroll
            for (int ww = 0; ww < 4; ++ww)
                #pragma unroll
                for (int c = 0; c < 3; ++c) {
                    float u  = mbuf[ww][pt][lp][c];
                    float t3 = __builtin_amdgcn_fmed3f(M2, M3, u);
                    float t2 = __builtin_amdgcn_fmed3f(M1, M2, u);
                    M1 = fminf(M1, u); M2 = t2; M3 = t3;
                }
            int ks[3] = {(int)(__float_as_uint(M1) & 1023u),
                         (int)(__float_as_uint(M2) & 1023u),
                         (int)(__float_as_uint(M3) & 1023u)};

            // re-read this position's 32 channels (L1/L2-hot)
            float xr[32];
            const float* xgp = x + b * CHW + s0 + pt * 16 + lp;
            #pragma unroll
            for (int cs = 0; cs < 4; ++cs)
                #pragma unroll
                for (int j = 0; j < 8; ++j)
                    xr[cs * 8 + j] = xgp[(32 * cs + 8 * q + j) * HW];

            // exact fp32 rescore of the 3 candidates (same order as R4-R14)
            float dots[3];
            #pragma unroll
            for (int jj = 0; jj < 3; ++jj) {
                const float* crow = cb + ks[jj] * C_DIM + 8 * q;
                float p = 0.f;
                #pragma unroll
                for (int cs = 0; cs < 4; ++cs) {
                    float4 a0 = *(const float4*)(crow + 32 * cs);
                    float4 a1 = *(const float4*)(crow + 32 * cs + 4);
                    p = fmaf(xr[cs*8+0], a0.x, p); p = fmaf(xr[cs*8+1], a0.y, p);
                    p = fmaf(xr[cs*8+2], a0.z, p); p = fmaf(xr[cs*8+3], a0.w, p);
                    p = fmaf(xr[cs*8+4], a1.x, p); p = fmaf(xr[cs*8+5], a1.y, p);
                    p = fmaf(xr[cs*8+6], a1.z, p); p = fmaf(xr[cs*8+7], a1.w, p);
                }
                p += __shfl_xor(p, 16);
                p += __shfl_xor(p, 32);
                dots[jj] = p;
            }
            float sb = fmaf(r2v[pt], dots[0], c2w[ks[0]]); int kb = ks[0];
            float s2 = fmaf(r2v[pt], dots[1], c2w[ks[1]]);
            if (s2 < sb || (s2 == sb && ks[1] < kb)) { sb = s2; kb = ks[1]; }
            float s3 = fmaf(r2v[pt], dots[2], c2w[ks[2]]);
            if (s3 < sb || (s3 == sb && ks[2] < kb)) { sb = s3; kb = ks[2]; }

            if (ln < 16) {
                idxw[bid * 64 + pt * 16 + lp] = kb;
                ibuf[pt * 16 + lp] = kb;         // publish for fused store
            }
            lsum += sqrtf(fmaxf(1.0f + sb, 0.f));   // z2 == 1 after normalize
        }
        // each position counted by its 4 q-lanes -> scale 0.25
        #pragma unroll
        for (int off = 32; off > 0; off >>= 1) lsum += __shfl_down(lsum, off);
        if (ln == 0) atomicAdd(Sw, 0.25f * lsum);
    }

    // ---- fused q-store (b>0; batch 0's region aliases cbbf -> write_q0) ----
    __syncthreads();                             // ibuf visible to all waves
    if (b != 0) {
        const int row = ibuf[ln];                // position s0+ln's code
        const float4* cbr = (const float4*)cb + row * 32;
        float* ob = out + b * CHW + s0 + ln;
        #pragma unroll
        for (int c4 = w * 8; c4 < w * 8 + 8; ++c4) {   // wave w: 32 channels
            float4 v = cbr[c4];                  // 16B gather, L2-hot
            float* o = ob + (c4 * 4) * HW;
            o[0]      = v.x;                     // each store: 64 lanes x 4B
            o[HW]     = v.y;                     //  = coalesced 256B segment
            o[2 * HW] = v.z;
            o[3 * HW] = v.w;
        }
    }
}

// ---------------------------------------------------------------------------
// Kernel 3: batch-0 scatter (region was cbbf scratch during vq) + losses.
// ---------------------------------------------------------------------------
__global__ void write_q0(const float* __restrict__ cb,
                         const int* __restrict__ idxw,
                         const float* __restrict__ ws,
                         float* __restrict__ out) {
    int id = blockIdx.x * 256 + threadIdx.x;   // 131072 = 4096 * 32
    int s  = id & 4095;                        // spatial (lanes consecutive)
    int c4 = id >> 12;                         // channel quad 0..31
    int row = idxw[s];                         // batch 0 -> p == s
    float4 v = ((const float4*)cb)[row * 32 + c4];   // 16B gather, L2-hot
    float* o = out + (c4 * 4) * HW + s;        // b = 0
    o[0]      = v.x;
    o[HW]     = v.y;
    o[2 * HW] = v.z;
    o[3 * HW] = v.w;
    if (id == 0) {                             // loss finalize (after vq)
        float S = *(const float*)((const char*)ws + WS_S);
        float m = S / (float)N_POS;
        out[Q_ELEMS]     = 0.25f * m;
        out[Q_ELEMS + 1] = m;
    }
}

extern "C" void kernel_launch(void* const* d_in, const int* in_sizes, int n_in,
                              void* d_out, int out_size, void* d_ws, size_t ws_size,
                              hipStream_t stream) {
    const float* x  = (const float*)d_in[0];   // [16,128,64,64]
    const float* cb = (const float*)d_in[1];   // [1024,128]
    float* out = (float*)d_out;
    float* ws  = (float*)d_ws;

    const float* c2w = (const float*)((const char*)d_ws + WS_C2);
    int*  idxw = (int*)((char*)d_ws + WS_IDX);
    float* Sw  = (float*)((char*)d_ws + WS_S);
    unsigned short* cbbf = (unsigned short*)d_out;   // scratch in d_out

    prep_kernel<<<K_CODES, 64, 0, stream>>>(cb, ws, cbbf);
    vq_mfma    <<<N_POS / 64, 256, 0, stream>>>(x, cb, cbbf, c2w, idxw, Sw, out);
    write_q0   <<<512, 256, 0, stream>>>(cb, idxw, ws, out);
}

// Round 10
// 69.089 us; speedup vs baseline: 1.4580x; 1.0719x over previous
//
#include <hip/hip_runtime.h>
#include <hip/hip_bf16.h>
#include <math.h>

// Problem constants
#define K_CODES 1024
#define C_DIM   128
#define HW      4096          // 64*64
#define CHW     (C_DIM*HW)    // per-batch stride in x
#define N_POS   65536         // 16*64*64
#define Q_ELEMS 8388608       // 16*128*64*64

// ws layout (byte offsets).
#define WS_S    0             // float: sum of sqrt(d2min)
#define WS_C2   256           // float[1024]: ||c_k||^2
#define WS_IDX  8192          // int[65536]: final argmin index per position

// d_out scratch (overwritten later; stream-ordered, safe):
//   offset 0: bf16 codebook (256 KB), row k at k*256B, granule-col j holds
//   channels of granule (j ^ (k&7)) -> linear global_load_lds staging +
//   conflict-free swizzled ds_read_b128 A-frags. This region == q's
//   (b=0, c<16) slice, so b=0 blocks skip the fused q-store (write_q0
//   covers batch 0 after vq completes).

typedef __attribute__((ext_vector_type(8))) short short8;   // 8 bf16 (4 VGPRs)
typedef __attribute__((ext_vector_type(4))) float f32x4;    // MFMA acc

__device__ __forceinline__ unsigned short f2bf(float f) {   // fp32 -> bf16 RNE
    unsigned u = __float_as_uint(f);
    u += 0x7FFFu + ((u >> 16) & 1u);
    return (unsigned short)(u >> 16);
}

// async global->LDS, 16B per lane; LDS dst = wave-uniform base (+lane*16 by HW)
__device__ __forceinline__ void gll16(const void* g, void* l) {
    __builtin_amdgcn_global_load_lds(
        (const __attribute__((address_space(1))) void*)g,
        (__attribute__((address_space(3))) void*)l, 16, 0, 0);
}

// ---------------------------------------------------------------------------
// Kernel 1: prep. Block k (64 lanes): row norm, bf16 conversion into the
// COLUMN-SWIZZLED global layout, S zeroing. (unchanged)
// ---------------------------------------------------------------------------
__global__ void prep_kernel(const float* __restrict__ cb, float* __restrict__ ws,
                            unsigned short* __restrict__ cbbf) {
    __shared__ __align__(16) unsigned short srow[128];
    int k = blockIdx.x;
    int l = threadIdx.x;                       // 64 lanes = 1 wave
    if (k == 0 && l == 0) *(float*)((char*)ws + WS_S) = 0.f;
    float v1 = cb[k * C_DIM + l];
    float v2 = cb[k * C_DIM + 64 + l];
    int c1 = l, c2 = 64 + l;
    srow[(((c1 >> 3) ^ (k & 7)) << 3) | (c1 & 7)] = f2bf(v1);
    srow[(((c2 >> 3) ^ (k & 7)) << 3) | (c2 & 7)] = f2bf(v2);
    float ss = v1 * v1 + v2 * v2;
    #pragma unroll
    for (int off = 32; off > 0; off >>= 1) ss += __shfl_down(ss, off);
    if (l == 0) ((float*)((char*)ws + WS_C2))[k] = ss;
    __syncthreads();
    if (l < 16) ((uint4*)cbbf)[k * 16 + l] = ((const uint4*)srow)[l];
}

// ---------------------------------------------------------------------------
// Kernel 2: fused VQ. R16 = EXACT R13 (best: vq 64.1 us, total 68.36,
// absmax 0.0) + ONE change: the x-phase fp32->bf16 conversion uses
// __float22bfloat162_rn (compiler emits v_cvt_pk_bf16_f32, 2 channels/instr)
// instead of manual bit-twiddled RNE (~5 VALU/channel). Both are RNE ->
// bit-identical bf16 for normal inputs -> identical fragments, identical
// top-3 sets, identical rescore: absmax-0.0 by construction. Saves ~550
// VALU instr/wave in the highest-busy pipe (VALUBusy 34%).
// Everything else byte-identical to R13: wave-private staging (wave w owns
// code-quarter, 8 x 8KB chunks, dbuf, wave-local vmcnt sync, zero scan
// barriers), merge via mbuf, rescore waves 0/1 (32-pos atomic groups),
// fused q-store tail (b>0), write_q0 for batch 0.
// ---------------------------------------------------------------------------
__global__ __launch_bounds__(256, 2) void vq_mfma(const float* __restrict__ x,
                                                  const float* __restrict__ cb,
                                                  const unsigned short* __restrict__ cbbf,
                                                  const float* __restrict__ c2w,
                                                  int* __restrict__ idxw,
                                                  float* __restrict__ Sw,
                                                  float* __restrict__ out) {
    __shared__ __align__(16) unsigned short cbuf[2][4][4096]; // 2 x 4 x 8 KB
    __shared__ float mbuf[4][4][16][3];                       // 3 KB
    __shared__ int ibuf[64];                                  // 256 B

    const int t  = threadIdx.x;
    const int w  = t >> 6;                      // wave 0..3 = code quarter
    const int ln = t & 63;
    const int lp = ln & 15;                     // position lane (n index)
    const int q  = ln >> 4;                     // quad 0..3 (k sub-range)
    const int bid = blockIdx.x;
    const int b   = bid >> 6;                   // batch (64 blocks per image)
    const int s0  = (bid & 63) << 6;            // 64-position tile start

    // wave's quarter of the pre-swizzled bf16 codebook (64 KB)
    const char* gq = (const char*)cbbf + (w << 16);

    { // stage chunk 0 -> buf 0 NOW; latency hides under the x-phase
        const char* gs = gq + (ln << 4);
        char* ld = (char*)&cbuf[0][w][0];
        #pragma unroll
        for (int r = 0; r < 8; ++r) gll16(gs + r * 1024, ld + r * 1024);
    }

    // ---- x: bf16 B-frags (4 pos-tiles = all 64 positions) + norms ----
    short8 xf[4][4];
    float  r2v[4];
    {
        float ss[4];
        #pragma unroll
        for (int pt = 0; pt < 4; ++pt) {
            ss[pt] = 0.f;
            const float* xgp = x + b * CHW + s0 + pt * 16 + lp;
            #pragma unroll
            for (int cs = 0; cs < 4; ++cs) {
                float vv[8];
                #pragma unroll
                for (int j = 0; j < 8; ++j) {
                    vv[j] = xgp[(32 * cs + 8 * q + j) * HW];
                    ss[pt] = fmaf(vv[j], vv[j], ss[pt]);
                }
                union { short8 v; ushort2 s2[4]; } fu;
                #pragma unroll
                for (int jp = 0; jp < 4; ++jp) {   // v_cvt_pk_bf16_f32 (RNE)
                    union { __hip_bfloat162 h2; ushort2 u2; } cv;
                    cv.h2 = __float22bfloat162_rn(
                        make_float2(vv[2 * jp], vv[2 * jp + 1]));
                    fu.s2[jp] = cv.u2;
                }
                xf[pt][cs] = fu.v;
            }
        }
        #pragma unroll
        for (int pt = 0; pt < 4; ++pt) {
            float s = ss[pt];
            s += __shfl_xor(s, 16);
            s += __shfl_xor(s, 32);
            r2v[pt] = -2.0f / fmaxf(sqrtf(s), 1e-12f);  // F.normalize eps
        }
    }

    const float FMAX = __uint_as_float(0x7F7FFFFFu);
    float m1[4] = {FMAX, FMAX, FMAX, FMAX};
    float m2[4] = {FMAX, FMAX, FMAX, FMAX};
    float m3[4] = {FMAX, FMAX, FMAX, FMAX};

    // chunk 0 landed (wave-local; also drains x loads, long consumed)
    asm volatile("s_waitcnt vmcnt(0)" ::: "memory");
    __builtin_amdgcn_sched_barrier(0);

    for (int i = 0; i < 8; ++i) {               // 8 chunks x 32 codes
        if (i < 7) {                             // stage next chunk (private)
            asm volatile("s_waitcnt lgkmcnt(0)" ::: "memory");
            const char* gs = gq + (i + 1) * 8192 + (ln << 4);
            char* ld = (char*)&cbuf[(i + 1) & 1][w][0];
            #pragma unroll
            for (int r = 0; r < 8; ++r) gll16(gs + r * 1024, ld + r * 1024);
        }

        const int k0 = (w << 8) + (i << 5);
        const unsigned short* cbp = &cbuf[i & 1][w][0];

        f32x4 acc[2][4];
        #pragma unroll
        for (int ct = 0; ct < 2; ++ct)
            #pragma unroll
            for (int pt = 0; pt < 4; ++pt) acc[ct][pt] = 0;

        #pragma unroll
        for (int cs = 0; cs < 4; ++cs) {
            short8 ah[2];
            #pragma unroll
            for (int ct = 0; ct < 2; ++ct) {     // A[m=16ct+lp][k=32cs+8q+j]
                int g = (16 * ct + lp) * 16 + ((4 * cs + q) ^ (lp & 7));
                ah[ct] = *(const short8*)(cbp + g * 8);
            }
            #pragma unroll
            for (int ct = 0; ct < 2; ++ct)
                #pragma unroll
                for (int pt = 0; pt < 4; ++pt)
                    acc[ct][pt] = __builtin_amdgcn_mfma_f32_16x16x32_bf16(
                        ah[ct], xf[pt][cs], acc[ct][pt], 0, 0, 0);
        }

        // ---- epilogue: 32 scores/lane (2ct x 4pt x 4reg) ----
        #pragma unroll
        for (int ct = 0; ct < 2; ++ct) {
            float4 c2vv = *(const float4*)(c2w + k0 + 16 * ct + 4 * q);
            float c2a[4] = {c2vv.x, c2vv.y, c2vv.z, c2vv.w};
            const int kb0 = k0 + 16 * ct + 4 * q;
            #pragma unroll
            for (int pt = 0; pt < 4; ++pt) {
                #pragma unroll
                for (int reg = 0; reg < 4; ++reg) {
                    float s = fmaf(r2v[pt], acc[ct][pt][reg], c2a[reg]);
                    unsigned pb = (__float_as_uint(s) & 0xFFFFFC00u) |
                                  (unsigned)(kb0 + reg);
                    float u  = __uint_as_float(pb);
                    float t3 = __builtin_amdgcn_fmed3f(m2[pt], m3[pt], u);
                    float t2 = __builtin_amdgcn_fmed3f(m1[pt], m2[pt], u);
                    m1[pt] = fminf(m1[pt], u); m2[pt] = t2; m3[pt] = t3;
                }
            }
        }

        if (i < 7) {                             // next chunk landed (wave-local)
            asm volatile("s_waitcnt vmcnt(0)" ::: "memory");
            __builtin_amdgcn_sched_barrier(0);
        }
    }

    // ---- merge chains across the 4 quad-lanes (butterfly, all 4 pt) ----
    #pragma unroll
    for (int d = 16; d <= 32; d <<= 1) {
        #pragma unroll
        for (int pt = 0; pt < 4; ++pt) {
            float o1 = __shfl_xor(m1[pt], d), o2 = __shfl_xor(m2[pt], d),
                  o3 = __shfl_xor(m3[pt], d);
            float u, t2, t3;
            u = o1; t3 = __builtin_amdgcn_fmed3f(m2[pt], m3[pt], u);
            t2 = __builtin_amdgcn_fmed3f(m1[pt], m2[pt], u);
            m1[pt] = fminf(m1[pt], u); m2[pt] = t2; m3[pt] = t3;
            u = o2; t3 = __builtin_amdgcn_fmed3f(m2[pt], m3[pt], u);
            t2 = __builtin_amdgcn_fmed3f(m1[pt], m2[pt], u);
            m1[pt] = fminf(m1[pt], u); m2[pt] = t2; m3[pt] = t3;
            u = o3; t3 = __builtin_amdgcn_fmed3f(m2[pt], m3[pt], u);
            t2 = __builtin_amdgcn_fmed3f(m1[pt], m2[pt], u);
            m1[pt] = fminf(m1[pt], u); m2[pt] = t2; m3[pt] = t3;
        }
    }

    // publish all 4 per-quarter chains
    if (ln < 16) {
        #pragma unroll
        for (int pt = 0; pt < 4; ++pt) {
            mbuf[w][pt][lp][0] = m1[pt];
            mbuf[w][pt][lp][1] = m2[pt];
            mbuf[w][pt][lp][2] = m3[pt];
        }
    }
    __syncthreads();

    // ---- rescore: wave 0 -> positions 0-31 (pt 0,1), wave 1 -> 32-63 ----
    if (w < 2) {
        float lsum = 0.f;
        #pragma unroll
        for (int ptl = 0; ptl < 2; ++ptl) {
            const int pt = 2 * w + ptl;
            // merge the 4 quarters' chains (fixed order; unique top-3 set)
            float M1 = FMAX, M2 = FMAX, M3 = FMAX;
            #pragma unroll
            for (int ww = 0; ww < 4; ++ww)
                #pragma unroll
                for (int c = 0; c < 3; ++c) {
                    float u  = mbuf[ww][pt][lp][c];
                    float t3 = __builtin_amdgcn_fmed3f(M2, M3, u);
                    float t2 = __builtin_amdgcn_fmed3f(M1, M2, u);
                    M1 = fminf(M1, u); M2 = t2; M3 = t3;
                }
            int ks[3] = {(int)(__float_as_uint(M1) & 1023u),
                         (int)(__float_as_uint(M2) & 1023u),
                         (int)(__float_as_uint(M3) & 1023u)};

            // re-read this position's 32 channels (L1/L2-hot)
            float xr[32];
            const float* xgp = x + b * CHW + s0 + pt * 16 + lp;
            #pragma unroll
            for (int cs = 0; cs < 4; ++cs)
                #pragma unroll
                for (int j = 0; j < 8; ++j)
                    xr[cs * 8 + j] = xgp[(32 * cs + 8 * q + j) * HW];

            // exact fp32 rescore of the 3 candidates (same order as R4-R15)
            float dots[3];
            #pragma unroll
            for (int jj = 0; jj < 3; ++jj) {
                const float* crow = cb + ks[jj] * C_DIM + 8 * q;
                float p = 0.f;
                #pragma unroll
                for (int cs = 0; cs < 4; ++cs) {
                    float4 a0 = *(const float4*)(crow + 32 * cs);
                    float4 a1 = *(const float4*)(crow + 32 * cs + 4);
                    p = fmaf(xr[cs*8+0], a0.x, p); p = fmaf(xr[cs*8+1], a0.y, p);
                    p = fmaf(xr[cs*8+2], a0.z, p); p = fmaf(xr[cs*8+3], a0.w, p);
                    p = fmaf(xr[cs*8+4], a1.x, p); p = fmaf(xr[cs*8+5], a1.y, p);
                    p = fmaf(xr[cs*8+6], a1.z, p); p = fmaf(xr[cs*8+7], a1.w, p);
                }
                p += __shfl_xor(p, 16);
                p += __shfl_xor(p, 32);
                dots[jj] = p;
            }
            float sb = fmaf(r2v[pt], dots[0], c2w[ks[0]]); int kb = ks[0];
            float s2 = fmaf(r2v[pt], dots[1], c2w[ks[1]]);
            if (s2 < sb || (s2 == sb && ks[1] < kb)) { sb = s2; kb = ks[1]; }
            float s3 = fmaf(r2v[pt], dots[2], c2w[ks[2]]);
            if (s3 < sb || (s3 == sb && ks[2] < kb)) { sb = s3; kb = ks[2]; }

            if (ln < 16) {
                idxw[bid * 64 + pt * 16 + lp] = kb;
                ibuf[pt * 16 + lp] = kb;         // publish for fused store
            }
            lsum += sqrtf(fmaxf(1.0f + sb, 0.f));   // z2 == 1 after normalize
        }
        // each position counted by its 4 q-lanes -> scale 0.25
        #pragma unroll
        for (int off = 32; off > 0; off >>= 1) lsum += __shfl_down(lsum, off);
        if (ln == 0) atomicAdd(Sw, 0.25f * lsum);
    }

    // ---- fused q-store (b>0; batch 0's region aliases cbbf -> write_q0) ----
    __syncthreads();                             // ibuf visible to all waves
    if (b != 0) {
        const int row = ibuf[ln];                // position s0+ln's code
        const float4* cbr = (const float4*)cb + row * 32;
        float* ob = out + b * CHW + s0 + ln;
        #pragma unroll
        for (int c4 = w * 8; c4 < w * 8 + 8; ++c4) {   // wave w: 32 channels
            float4 v = cbr[c4];                  // 16B gather, L2-hot
            float* o = ob + (c4 * 4) * HW;
            o[0]      = v.x;                     // each store: 64 lanes x 4B
            o[HW]     = v.y;                     //  = coalesced 256B segment
            o[2 * HW] = v.z;
            o[3 * HW] = v.w;
        }
    }
}

// ---------------------------------------------------------------------------
// Kernel 3: batch-0 scatter (region was cbbf scratch during vq) + losses.
// ---------------------------------------------------------------------------
__global__ void write_q0(const float* __restrict__ cb,
                         const int* __restrict__ idxw,
                         const float* __restrict__ ws,
                         float* __restrict__ out) {
    int id = blockIdx.x * 256 + threadIdx.x;   // 131072 = 4096 * 32
    int s  = id & 4095;                        // spatial (lanes consecutive)
    int c4 = id >> 12;                         // channel quad 0..31
    int row = idxw[s];                         // batch 0 -> p == s
    float4 v = ((const float4*)cb)[row * 32 + c4];   // 16B gather, L2-hot
    float* o = out + (c4 * 4) * HW + s;        // b = 0
    o[0]      = v.x;
    o[HW]     = v.y;
    o[2 * HW] = v.z;
    o[3 * HW] = v.w;
    if (id == 0) {                             // loss finalize (after vq)
        float S = *(const float*)((const char*)ws + WS_S);
        float m = S / (float)N_POS;
        out[Q_ELEMS]     = 0.25f * m;
        out[Q_ELEMS + 1] = m;
    }
}

extern "C" void kernel_launch(void* const* d_in, const int* in_sizes, int n_in,
                              void* d_out, int out_size, void* d_ws, size_t ws_size,
                              hipStream_t stream) {
    const float* x  = (const float*)d_in[0];   // [16,128,64,64]
    const float* cb = (const float*)d_in[1];   // [1024,128]
    float* out = (float*)d_out;
    float* ws  = (float*)d_ws;

    const float* c2w = (const float*)((const char*)d_ws + WS_C2);
    int*  idxw = (int*)((char*)d_ws + WS_IDX);
    float* Sw  = (float*)((char*)d_ws + WS_S);
    unsigned short* cbbf = (unsigned short*)d_out;   // scratch in d_out

    prep_kernel<<<K_CODES, 64, 0, stream>>>(cb, ws, cbbf);
    vq_mfma    <<<N_POS / 64, 256, 0, stream>>>(x, cb, cbbf, c2w, idxw, Sw, out);
    write_q0   <<<512, 256, 0, stream>>>(cb, idxw, ws, out);
}

// Round 11
// 68.424 us; speedup vs baseline: 1.4721x; 1.0097x over previous
//
#include <hip/hip_runtime.h>
#include <math.h>

// Problem constants
#define K_CODES 1024
#define C_DIM   128
#define HW      4096          // 64*64
#define CHW     (C_DIM*HW)    // per-batch stride in x
#define N_POS   65536         // 16*64*64
#define Q_ELEMS 8388608       // 16*128*64*64

// ws layout (byte offsets).
#define WS_S    0             // float: sum of sqrt(d2min)
#define WS_C2   256           // float[1024]: ||c_k||^2
#define WS_IDX  8192          // int[65536]: final argmin index per position

// d_out scratch (overwritten later; stream-ordered, safe):
//   offset 0: bf16 codebook (256 KB), row k at k*256B, granule-col j holds
//   channels of granule (j ^ (k&7)) -> linear global_load_lds staging +
//   conflict-free swizzled ds_read_b128 A-frags. This region == q's
//   (b=0, c<16) slice, so b=0 blocks skip the fused q-store (write_q0
//   covers batch 0 after vq completes).

typedef __attribute__((ext_vector_type(8))) short short8;   // 8 bf16 (4 VGPRs)
typedef __attribute__((ext_vector_type(4))) float f32x4;    // MFMA acc

__device__ __forceinline__ unsigned short f2bf(float f) {   // fp32 -> bf16 RNE
    unsigned u = __float_as_uint(f);
    u += 0x7FFFu + ((u >> 16) & 1u);
    return (unsigned short)(u >> 16);
}

// async global->LDS, 16B per lane; LDS dst = wave-uniform base (+lane*16 by HW)
__device__ __forceinline__ void gll16(const void* g, void* l) {
    __builtin_amdgcn_global_load_lds(
        (const __attribute__((address_space(1))) void*)g,
        (__attribute__((address_space(3))) void*)l, 16, 0, 0);
}

// ---------------------------------------------------------------------------
// Kernel 1: prep. Block k (64 lanes): row norm, bf16 conversion into the
// COLUMN-SWIZZLED global layout, S zeroing. (unchanged)
// ---------------------------------------------------------------------------
__global__ void prep_kernel(const float* __restrict__ cb, float* __restrict__ ws,
                            unsigned short* __restrict__ cbbf) {
    __shared__ __align__(16) unsigned short srow[128];
    int k = blockIdx.x;
    int l = threadIdx.x;                       // 64 lanes = 1 wave
    if (k == 0 && l == 0) *(float*)((char*)ws + WS_S) = 0.f;
    float v1 = cb[k * C_DIM + l];
    float v2 = cb[k * C_DIM + 64 + l];
    int c1 = l, c2 = 64 + l;
    srow[(((c1 >> 3) ^ (k & 7)) << 3) | (c1 & 7)] = f2bf(v1);
    srow[(((c2 >> 3) ^ (k & 7)) << 3) | (c2 & 7)] = f2bf(v2);
    float ss = v1 * v1 + v2 * v2;
    #pragma unroll
    for (int off = 32; off > 0; off >>= 1) ss += __shfl_down(ss, off);
    if (l == 0) ((float*)((char*)ws + WS_C2))[k] = ss;
    __syncthreads();
    if (l < 16) ((uint4*)cbbf)[k * 16 + l] = ((const uint4*)srow)[l];
}

// ---------------------------------------------------------------------------
// Kernel 2: fused VQ. R17 = EXACT R13 (session best: vq 64.1 us, total
// 68.36 us, absmax 0.0). Wave-private staging, barrier-free scan: 1024
// blocks x 256 thr (4 waves), block = 64 positions; wave w owns code-quarter
// [w*256,(w+1)*256) for ALL 64 positions (xf[4 pt]); each 8 KB chunk (32
// codes) double-buffered in the wave's PRIVATE LDS region, synced with
// wave-local s_waitcnt vmcnt(0) (zero scan barriers). ds_read traffic and
// bank conflicts are half of the shared-staging variants (each chunk read
// by exactly one wave). Session evidence (R7-R16): this is the measured
// optimum of the structure family; occupancy-, barrier-, and VALU-directed
// perturbations are all neutral or negative. Merge via mbuf, rescore waves
// 0/1 (R6's exact per-atomic partials and trees), fused q-store tail (b>0),
// write_q0 covers batch 0.
// ---------------------------------------------------------------------------
__global__ __launch_bounds__(256, 2) void vq_mfma(const float* __restrict__ x,
                                                  const float* __restrict__ cb,
                                                  const unsigned short* __restrict__ cbbf,
                                                  const float* __restrict__ c2w,
                                                  int* __restrict__ idxw,
                                                  float* __restrict__ Sw,
                                                  float* __restrict__ out) {
    __shared__ __align__(16) unsigned short cbuf[2][4][4096]; // 2 x 4 x 8 KB
    __shared__ float mbuf[4][4][16][3];                       // 3 KB
    __shared__ int ibuf[64];                                  // 256 B

    const int t  = threadIdx.x;
    const int w  = t >> 6;                      // wave 0..3 = code quarter
    const int ln = t & 63;
    const int lp = ln & 15;                     // position lane (n index)
    const int q  = ln >> 4;                     // quad 0..3 (k sub-range)
    const int bid = blockIdx.x;
    const int b   = bid >> 6;                   // batch (64 blocks per image)
    const int s0  = (bid & 63) << 6;            // 64-position tile start

    // wave's quarter of the pre-swizzled bf16 codebook (64 KB)
    const char* gq = (const char*)cbbf + (w << 16);

    { // stage chunk 0 -> buf 0 NOW; latency hides under the x-phase
        const char* gs = gq + (ln << 4);
        char* ld = (char*)&cbuf[0][w][0];
        #pragma unroll
        for (int r = 0; r < 8; ++r) gll16(gs + r * 1024, ld + r * 1024);
    }

    // ---- x: bf16 B-frags (4 pos-tiles = all 64 positions) + norms ----
    short8 xf[4][4];
    float  r2v[4];
    {
        float ss[4];
        #pragma unroll
        for (int pt = 0; pt < 4; ++pt) {
            ss[pt] = 0.f;
            const float* xgp = x + b * CHW + s0 + pt * 16 + lp;
            #pragma unroll
            for (int cs = 0; cs < 4; ++cs) {
                union { short8 v; unsigned short u[8]; } fu;
                #pragma unroll
                for (int j = 0; j < 8; ++j) {
                    float vv = xgp[(32 * cs + 8 * q + j) * HW];
                    ss[pt] = fmaf(vv, vv, ss[pt]);
                    fu.u[j] = f2bf(vv);
                }
                xf[pt][cs] = fu.v;
            }
        }
        #pragma unroll
        for (int pt = 0; pt < 4; ++pt) {
            float s = ss[pt];
            s += __shfl_xor(s, 16);
            s += __shfl_xor(s, 32);
            r2v[pt] = -2.0f / fmaxf(sqrtf(s), 1e-12f);  // F.normalize eps
        }
    }

    const float FMAX = __uint_as_float(0x7F7FFFFFu);
    float m1[4] = {FMAX, FMAX, FMAX, FMAX};
    float m2[4] = {FMAX, FMAX, FMAX, FMAX};
    float m3[4] = {FMAX, FMAX, FMAX, FMAX};

    // chunk 0 landed (wave-local; also drains x loads, long consumed)
    asm volatile("s_waitcnt vmcnt(0)" ::: "memory");
    __builtin_amdgcn_sched_barrier(0);

    for (int i = 0; i < 8; ++i) {               // 8 chunks x 32 codes
        if (i < 7) {                             // stage next chunk (private)
            asm volatile("s_waitcnt lgkmcnt(0)" ::: "memory");
            const char* gs = gq + (i + 1) * 8192 + (ln << 4);
            char* ld = (char*)&cbuf[(i + 1) & 1][w][0];
            #pragma unroll
            for (int r = 0; r < 8; ++r) gll16(gs + r * 1024, ld + r * 1024);
        }

        const int k0 = (w << 8) + (i << 5);
        const unsigned short* cbp = &cbuf[i & 1][w][0];

        f32x4 acc[2][4];
        #pragma unroll
        for (int ct = 0; ct < 2; ++ct)
            #pragma unroll
            for (int pt = 0; pt < 4; ++pt) acc[ct][pt] = 0;

        #pragma unroll
        for (int cs = 0; cs < 4; ++cs) {
            short8 ah[2];
            #pragma unroll
            for (int ct = 0; ct < 2; ++ct) {     // A[m=16ct+lp][k=32cs+8q+j]
                int g = (16 * ct + lp) * 16 + ((4 * cs + q) ^ (lp & 7));
                ah[ct] = *(const short8*)(cbp + g * 8);
            }
            #pragma unroll
            for (int ct = 0; ct < 2; ++ct)
                #pragma unroll
                for (int pt = 0; pt < 4; ++pt)
                    acc[ct][pt] = __builtin_amdgcn_mfma_f32_16x16x32_bf16(
                        ah[ct], xf[pt][cs], acc[ct][pt], 0, 0, 0);
        }

        // ---- epilogue: 32 scores/lane (2ct x 4pt x 4reg) ----
        #pragma unroll
        for (int ct = 0; ct < 2; ++ct) {
            float4 c2vv = *(const float4*)(c2w + k0 + 16 * ct + 4 * q);
            float c2a[4] = {c2vv.x, c2vv.y, c2vv.z, c2vv.w};
            const int kb0 = k0 + 16 * ct + 4 * q;
            #pragma unroll
            for (int pt = 0; pt < 4; ++pt) {
                #pragma unroll
                for (int reg = 0; reg < 4; ++reg) {
                    float s = fmaf(r2v[pt], acc[ct][pt][reg], c2a[reg]);
                    unsigned pb = (__float_as_uint(s) & 0xFFFFFC00u) |
                                  (unsigned)(kb0 + reg);
                    float u  = __uint_as_float(pb);
                    float t3 = __builtin_amdgcn_fmed3f(m2[pt], m3[pt], u);
                    float t2 = __builtin_amdgcn_fmed3f(m1[pt], m2[pt], u);
                    m1[pt] = fminf(m1[pt], u); m2[pt] = t2; m3[pt] = t3;
                }
            }
        }

        if (i < 7) {                             // next chunk landed (wave-local)
            asm volatile("s_waitcnt vmcnt(0)" ::: "memory");
            __builtin_amdgcn_sched_barrier(0);
        }
    }

    // ---- merge chains across the 4 quad-lanes (butterfly, all 4 pt) ----
    #pragma unroll
    for (int d = 16; d <= 32; d <<= 1) {
        #pragma unroll
        for (int pt = 0; pt < 4; ++pt) {
            float o1 = __shfl_xor(m1[pt], d), o2 = __shfl_xor(m2[pt], d),
                  o3 = __shfl_xor(m3[pt], d);
            float u, t2, t3;
            u = o1; t3 = __builtin_amdgcn_fmed3f(m2[pt], m3[pt], u);
            t2 = __builtin_amdgcn_fmed3f(m1[pt], m2[pt], u);
            m1[pt] = fminf(m1[pt], u); m2[pt] = t2; m3[pt] = t3;
            u = o2; t3 = __builtin_amdgcn_fmed3f(m2[pt], m3[pt], u);
            t2 = __builtin_amdgcn_fmed3f(m1[pt], m2[pt], u);
            m1[pt] = fminf(m1[pt], u); m2[pt] = t2; m3[pt] = t3;
            u = o3; t3 = __builtin_amdgcn_fmed3f(m2[pt], m3[pt], u);
            t2 = __builtin_amdgcn_fmed3f(m1[pt], m2[pt], u);
            m1[pt] = fminf(m1[pt], u); m2[pt] = t2; m3[pt] = t3;
        }
    }

    // publish all 4 per-quarter chains
    if (ln < 16) {
        #pragma unroll
        for (int pt = 0; pt < 4; ++pt) {
            mbuf[w][pt][lp][0] = m1[pt];
            mbuf[w][pt][lp][1] = m2[pt];
            mbuf[w][pt][lp][2] = m3[pt];
        }
    }
    __syncthreads();

    // ---- rescore: wave 0 -> positions 0-31 (pt 0,1), wave 1 -> 32-63 ----
    if (w < 2) {
        float lsum = 0.f;
        #pragma unroll
        for (int ptl = 0; ptl < 2; ++ptl) {
            const int pt = 2 * w + ptl;
            // merge the 4 quarters' chains (fixed order; unique top-3 set)
            float M1 = FMAX, M2 = FMAX, M3 = FMAX;
            #pragma unroll
            for (int ww = 0; ww < 4; ++ww)
                #pragma unroll
                for (int c = 0; c < 3; ++c) {
                    float u  = mbuf[ww][pt][lp][c];
                    float t3 = __builtin_amdgcn_fmed3f(M2, M3, u);
                    float t2 = __builtin_amdgcn_fmed3f(M1, M2, u);
                    M1 = fminf(M1, u); M2 = t2; M3 = t3;
                }
            int ks[3] = {(int)(__float_as_uint(M1) & 1023u),
                         (int)(__float_as_uint(M2) & 1023u),
                         (int)(__float_as_uint(M3) & 1023u)};

            // re-read this position's 32 channels (L1/L2-hot)
            float xr[32];
            const float* xgp = x + b * CHW + s0 + pt * 16 + lp;
            #pragma unroll
            for (int cs = 0; cs < 4; ++cs)
                #pragma unroll
                for (int j = 0; j < 8; ++j)
                    xr[cs * 8 + j] = xgp[(32 * cs + 8 * q + j) * HW];

            // exact fp32 rescore of the 3 candidates (same order as R4-R16)
            float dots[3];
            #pragma unroll
            for (int jj = 0; jj < 3; ++jj) {
                const float* crow = cb + ks[jj] * C_DIM + 8 * q;
                float p = 0.f;
                #pragma unroll
                for (int cs = 0; cs < 4; ++cs) {
                    float4 a0 = *(const float4*)(crow + 32 * cs);
                    float4 a1 = *(const float4*)(crow + 32 * cs + 4);
                    p = fmaf(xr[cs*8+0], a0.x, p); p = fmaf(xr[cs*8+1], a0.y, p);
                    p = fmaf(xr[cs*8+2], a0.z, p); p = fmaf(xr[cs*8+3], a0.w, p);
                    p = fmaf(xr[cs*8+4], a1.x, p); p = fmaf(xr[cs*8+5], a1.y, p);
                    p = fmaf(xr[cs*8+6], a1.z, p); p = fmaf(xr[cs*8+7], a1.w, p);
                }
                p += __shfl_xor(p, 16);
                p += __shfl_xor(p, 32);
                dots[jj] = p;
            }
            float sb = fmaf(r2v[pt], dots[0], c2w[ks[0]]); int kb = ks[0];
            float s2 = fmaf(r2v[pt], dots[1], c2w[ks[1]]);
            if (s2 < sb || (s2 == sb && ks[1] < kb)) { sb = s2; kb = ks[1]; }
            float s3 = fmaf(r2v[pt], dots[2], c2w[ks[2]]);
            if (s3 < sb || (s3 == sb && ks[2] < kb)) { sb = s3; kb = ks[2]; }

            if (ln < 16) {
                idxw[bid * 64 + pt * 16 + lp] = kb;
                ibuf[pt * 16 + lp] = kb;         // publish for fused store
            }
            lsum += sqrtf(fmaxf(1.0f + sb, 0.f));   // z2 == 1 after normalize
        }
        // each position counted by its 4 q-lanes -> scale 0.25
        #pragma unroll
        for (int off = 32; off > 0; off >>= 1) lsum += __shfl_down(lsum, off);
        if (ln == 0) atomicAdd(Sw, 0.25f * lsum);
    }

    // ---- fused q-store (b>0; batch 0's region aliases cbbf -> write_q0) ----
    __syncthreads();                             // ibuf visible to all waves
    if (b != 0) {
        const int row = ibuf[ln];                // position s0+ln's code
        const float4* cbr = (const float4*)cb + row * 32;
        float* ob = out + b * CHW + s0 + ln;
        #pragma unroll
        for (int c4 = w * 8; c4 < w * 8 + 8; ++c4) {   // wave w: 32 channels
            float4 v = cbr[c4];                  // 16B gather, L2-hot
            float* o = ob + (c4 * 4) * HW;
            o[0]      = v.x;                     // each store: 64 lanes x 4B
            o[HW]     = v.y;                     //  = coalesced 256B segment
            o[2 * HW] = v.z;
            o[3 * HW] = v.w;
        }
    }
}

// ---------------------------------------------------------------------------
// Kernel 3: batch-0 scatter (region was cbbf scratch during vq) + losses.
// ---------------------------------------------------------------------------
__global__ void write_q0(const float* __restrict__ cb,
                         const int* __restrict__ idxw,
                         const float* __restrict__ ws,
                         float* __restrict__ out) {
    int id = blockIdx.x * 256 + threadIdx.x;   // 131072 = 4096 * 32
    int s  = id & 4095;                        // spatial (lanes consecutive)
    int c4 = id >> 12;                         // channel quad 0..31
    int row = idxw[s];                         // batch 0 -> p == s
    float4 v = ((const float4*)cb)[row * 32 + c4];   // 16B gather, L2-hot
    float* o = out + (c4 * 4) * HW + s;        // b = 0
    o[0]      = v.x;
    o[HW]     = v.y;
    o[2 * HW] = v.z;
    o[3 * HW] = v.w;
    if (id == 0) {                             // loss finalize (after vq)
        float S = *(const float*)((const char*)ws + WS_S);
        float m = S / (float)N_POS;
        out[Q_ELEMS]     = 0.25f * m;
        out[Q_ELEMS + 1] = m;
    }
}

extern "C" void kernel_launch(void* const* d_in, const int* in_sizes, int n_in,
                              void* d_out, int out_size, void* d_ws, size_t ws_size,
                              hipStream_t stream) {
    const float* x  = (const float*)d_in[0];   // [16,128,64,64]
    const float* cb = (const float*)d_in[1];   // [1024,128]
    float* out = (float*)d_out;
    float* ws  = (float*)d_ws;

    const float* c2w = (const float*)((const char*)d_ws + WS_C2);
    int*  idxw = (int*)((char*)d_ws + WS_IDX);
    float* Sw  = (float*)((char*)d_ws + WS_S);
    unsigned short* cbbf = (unsigned short*)d_out;   // scratch in d_out

    prep_kernel<<<K_CODES, 64, 0, stream>>>(cb, ws, cbbf);
    vq_mfma    <<<N_POS / 64, 256, 0, stream>>>(x, cb, cbbf, c2w, idxw, Sw, out);
    write_q0   <<<512, 256, 0, stream>>>(cb, idxw, ws, out);
}

// Round 12
// 66.759 us; speedup vs baseline: 1.5088x; 1.0249x over previous
//
#include <hip/hip_runtime.h>
#include <math.h>

// Problem constants
#define K_CODES 1024
#define C_DIM   128
#define HW      4096          // 64*64
#define CHW     (C_DIM*HW)    // per-batch stride in x
#define N_POS   65536         // 16*64*64
#define Q_ELEMS 8388608       // 16*128*64*64

// ws layout (byte offsets).
#define WS_S    0             // float: sum of sqrt(d2min)
#define WS_C2   256           // float[1024]: ||c_k||^2
#define WS_IDX  8192          // int[65536]: final argmin index per position

// d_out scratch (overwritten later; stream-ordered, safe):
//   offset 0: bf16 codebook (256 KB), row k at k*256B, granule-col j holds
//   channels of granule (j ^ (k&7)) -> linear global_load_lds staging +
//   conflict-free swizzled ds_read_b128 A-frags. This region == q's
//   (b=0, c<16) slice, so b=0 blocks skip the fused q-store (write_q0
//   covers batch 0 after vq completes).

typedef __attribute__((ext_vector_type(8))) short short8;   // 8 bf16 (4 VGPRs)
typedef __attribute__((ext_vector_type(4))) float f32x4;    // MFMA acc

__device__ __forceinline__ unsigned short f2bf(float f) {   // fp32 -> bf16 RNE
    unsigned u = __float_as_uint(f);
    u += 0x7FFFu + ((u >> 16) & 1u);
    return (unsigned short)(u >> 16);
}

// async global->LDS, 16B per lane; LDS dst = wave-uniform base (+lane*16 by HW)
__device__ __forceinline__ void gll16(const void* g, void* l) {
    __builtin_amdgcn_global_load_lds(
        (const __attribute__((address_space(1))) void*)g,
        (__attribute__((address_space(3))) void*)l, 16, 0, 0);
}

// ---------------------------------------------------------------------------
// Kernel 1: prep. Block k (64 lanes): row norm, bf16 conversion into the
// COLUMN-SWIZZLED global layout, S zeroing. (unchanged)
// ---------------------------------------------------------------------------
__global__ void prep_kernel(const float* __restrict__ cb, float* __restrict__ ws,
                            unsigned short* __restrict__ cbbf) {
    __shared__ __align__(16) unsigned short srow[128];
    int k = blockIdx.x;
    int l = threadIdx.x;                       // 64 lanes = 1 wave
    if (k == 0 && l == 0) *(float*)((char*)ws + WS_S) = 0.f;
    float v1 = cb[k * C_DIM + l];
    float v2 = cb[k * C_DIM + 64 + l];
    int c1 = l, c2 = 64 + l;
    srow[(((c1 >> 3) ^ (k & 7)) << 3) | (c1 & 7)] = f2bf(v1);
    srow[(((c2 >> 3) ^ (k & 7)) << 3) | (c2 & 7)] = f2bf(v2);
    float ss = v1 * v1 + v2 * v2;
    #pragma unroll
    for (int off = 32; off > 0; off >>= 1) ss += __shfl_down(ss, off);
    if (l == 0) ((float*)((char*)ws + WS_C2))[k] = ss;
    __syncthreads();
    if (l < 16) ((uint4*)cbbf)[k * 16 + l] = ((const uint4*)srow)[l];
}

// ---------------------------------------------------------------------------
// Kernel 2: fused VQ. R18 = R13/R17 scan (session best, absmax 0.0) with a
// DEDUPED x-PROLOGUE. R13 had all 4 waves loading + converting the SAME
// 8192 x values (4x redundant, 4x64B-segment strided loads). Now: thread
// (w,ln) loads channels w*32..+31 of position s0+ln -- every load is one
// fully-coalesced 256B segment (128 instrs/block instead of 512, f2bf /4)
// -- converts, and writes 16B granules into an LDS transpose buffer using
// the SAME XOR-granule swizzle as the codebook (col = G ^ (pos&7)), so
// fragment reads are the identical conflict-free b128 pattern. xbuf (16 KB)
// ALIASES cbuf[1], which is dead until chunk-1 staging; fragment reads are
// fenced (lgkmcnt(0) + barrier) before the scan's first gll16 into that
// region. Fragment bf16 bits identical; per-position norm is summed in a
// different fixed order (w-partials, pairwise) -> r2v may differ ~1 ulp;
// scan+rescore both use the same r2v, and the argmin tie margin is
// empirically large (17 rounds of exact matches across reordered arith).
// Scan loop, chains, merge, rescore, fused q-store: byte-identical to R17.
// ---------------------------------------------------------------------------
__global__ __launch_bounds__(256, 2) void vq_mfma(const float* __restrict__ x,
                                                  const float* __restrict__ cb,
                                                  const unsigned short* __restrict__ cbbf,
                                                  const float* __restrict__ c2w,
                                                  int* __restrict__ idxw,
                                                  float* __restrict__ Sw,
                                                  float* __restrict__ out) {
    __shared__ __align__(16) unsigned short cbuf[2][4][4096]; // 2 x 4 x 8 KB
    __shared__ float mbuf[4][4][16][3];                       // 3 KB
    __shared__ float nbuf[4][64];                             // 1 KB norms
    __shared__ int ibuf[64];                                  // 256 B

    const int t  = threadIdx.x;
    const int w  = t >> 6;                      // wave 0..3 = code quarter
    const int ln = t & 63;
    const int lp = ln & 15;                     // position lane (n index)
    const int q  = ln >> 4;                     // quad 0..3 (k sub-range)
    const int bid = blockIdx.x;
    const int b   = bid >> 6;                   // batch (64 blocks per image)
    const int s0  = (bid & 63) << 6;            // 64-position tile start

    // wave's quarter of the pre-swizzled bf16 codebook (64 KB)
    const char* gq = (const char*)cbbf + (w << 16);

    { // stage chunk 0 -> buf 0 NOW; latency hides under the x-prologue
        const char* gs = gq + (ln << 4);
        char* ld = (char*)&cbuf[0][w][0];
        #pragma unroll
        for (int r = 0; r < 8; ++r) gll16(gs + r * 1024, ld + r * 1024);
    }

    // ---- x-prologue: ONE coalesced load + convert per value, shared via
    //      LDS transpose buffer (aliases cbuf[1]; dead until chunk-1) ----
    unsigned short* xbuf = &cbuf[1][0][0];       // 64 pos x 128 ch bf16, 16 KB
    {
        float ssp = 0.f;
        const float* xgp = x + b * CHW + (w * 32) * HW + s0 + ln;
        #pragma unroll
        for (int g = 0; g < 4; ++g) {            // granule = 8 channels, 16B
            union { short8 v; unsigned short u[8]; } fu;
            #pragma unroll
            for (int j = 0; j < 8; ++j) {
                float vv = xgp[(g * 8 + j) * HW];   // 256B coalesced segment
                ssp = fmaf(vv, vv, ssp);
                fu.u[j] = f2bf(vv);
            }
            int col = (w * 4 + g) ^ (ln & 7);    // same swizzle family as cb
            *(short8*)(xbuf + ln * 128 + col * 8) = fu.v;
        }
        nbuf[w][ln] = ssp;                       // partial over w's 32 ch
    }
    __syncthreads();                             // xbuf + nbuf complete

    // norms: fixed pairwise order over the 4 wave-partials
    float r2v[4];
    #pragma unroll
    for (int pt = 0; pt < 4; ++pt) {
        const int pos = pt * 16 + lp;
        float s01 = nbuf[0][pos] + nbuf[1][pos];
        float s23 = nbuf[2][pos] + nbuf[3][pos];
        float s   = s01 + s23;
        r2v[pt] = -2.0f / fmaxf(sqrtf(s), 1e-12f);  // F.normalize eps
    }

    // fragments: identical layout/order as before (bit-identical bf16)
    short8 xf[4][4];
    #pragma unroll
    for (int pt = 0; pt < 4; ++pt)
        #pragma unroll
        for (int cs = 0; cs < 4; ++cs) {
            int col = (4 * cs + q) ^ (lp & 7);   // (pt*16+lp)&7 == lp&7
            xf[pt][cs] = *(const short8*)(xbuf + (pt * 16 + lp) * 128 + col * 8);
        }
    asm volatile("s_waitcnt lgkmcnt(0)" ::: "memory");  // xf live in regs
    __builtin_amdgcn_sched_barrier(0);
    __syncthreads();                             // xbuf free for chunk-1 staging

    const float FMAX = __uint_as_float(0x7F7FFFFFu);
    float m1[4] = {FMAX, FMAX, FMAX, FMAX};
    float m2[4] = {FMAX, FMAX, FMAX, FMAX};
    float m3[4] = {FMAX, FMAX, FMAX, FMAX};

    // chunk 0 landed (barrier drained vmcnt; belt-and-suspenders wave-local)
    asm volatile("s_waitcnt vmcnt(0)" ::: "memory");
    __builtin_amdgcn_sched_barrier(0);

    for (int i = 0; i < 8; ++i) {               // 8 chunks x 32 codes
        if (i < 7) {                             // stage next chunk (private)
            asm volatile("s_waitcnt lgkmcnt(0)" ::: "memory");
            const char* gs = gq + (i + 1) * 8192 + (ln << 4);
            char* ld = (char*)&cbuf[(i + 1) & 1][w][0];
            #pragma unroll
            for (int r = 0; r < 8; ++r) gll16(gs + r * 1024, ld + r * 1024);
        }

        const int k0 = (w << 8) + (i << 5);
        const unsigned short* cbp = &cbuf[i & 1][w][0];

        f32x4 acc[2][4];
        #pragma unroll
        for (int ct = 0; ct < 2; ++ct)
            #pragma unroll
            for (int pt = 0; pt < 4; ++pt) acc[ct][pt] = 0;

        #pragma unroll
        for (int cs = 0; cs < 4; ++cs) {
            short8 ah[2];
            #pragma unroll
            for (int ct = 0; ct < 2; ++ct) {     // A[m=16ct+lp][k=32cs+8q+j]
                int g = (16 * ct + lp) * 16 + ((4 * cs + q) ^ (lp & 7));
                ah[ct] = *(const short8*)(cbp + g * 8);
            }
            #pragma unroll
            for (int ct = 0; ct < 2; ++ct)
                #pragma unroll
                for (int pt = 0; pt < 4; ++pt)
                    acc[ct][pt] = __builtin_amdgcn_mfma_f32_16x16x32_bf16(
                        ah[ct], xf[pt][cs], acc[ct][pt], 0, 0, 0);
        }

        // ---- epilogue: 32 scores/lane (2ct x 4pt x 4reg) ----
        #pragma unroll
        for (int ct = 0; ct < 2; ++ct) {
            float4 c2vv = *(const float4*)(c2w + k0 + 16 * ct + 4 * q);
            float c2a[4] = {c2vv.x, c2vv.y, c2vv.z, c2vv.w};
            const int kb0 = k0 + 16 * ct + 4 * q;
            #pragma unroll
            for (int pt = 0; pt < 4; ++pt) {
                #pragma unroll
                for (int reg = 0; reg < 4; ++reg) {
                    float s = fmaf(r2v[pt], acc[ct][pt][reg], c2a[reg]);
                    unsigned pb = (__float_as_uint(s) & 0xFFFFFC00u) |
                                  (unsigned)(kb0 + reg);
                    float u  = __uint_as_float(pb);
                    float t3 = __builtin_amdgcn_fmed3f(m2[pt], m3[pt], u);
                    float t2 = __builtin_amdgcn_fmed3f(m1[pt], m2[pt], u);
                    m1[pt] = fminf(m1[pt], u); m2[pt] = t2; m3[pt] = t3;
                }
            }
        }

        if (i < 7) {                             // next chunk landed (wave-local)
            asm volatile("s_waitcnt vmcnt(0)" ::: "memory");
            __builtin_amdgcn_sched_barrier(0);
        }
    }

    // ---- merge chains across the 4 quad-lanes (butterfly, all 4 pt) ----
    #pragma unroll
    for (int d = 16; d <= 32; d <<= 1) {
        #pragma unroll
        for (int pt = 0; pt < 4; ++pt) {
            float o1 = __shfl_xor(m1[pt], d), o2 = __shfl_xor(m2[pt], d),
                  o3 = __shfl_xor(m3[pt], d);
            float u, t2, t3;
            u = o1; t3 = __builtin_amdgcn_fmed3f(m2[pt], m3[pt], u);
            t2 = __builtin_amdgcn_fmed3f(m1[pt], m2[pt], u);
            m1[pt] = fminf(m1[pt], u); m2[pt] = t2; m3[pt] = t3;
            u = o2; t3 = __builtin_amdgcn_fmed3f(m2[pt], m3[pt], u);
            t2 = __builtin_amdgcn_fmed3f(m1[pt], m2[pt], u);
            m1[pt] = fminf(m1[pt], u); m2[pt] = t2; m3[pt] = t3;
            u = o3; t3 = __builtin_amdgcn_fmed3f(m2[pt], m3[pt], u);
            t2 = __builtin_amdgcn_fmed3f(m1[pt], m2[pt], u);
            m1[pt] = fminf(m1[pt], u); m2[pt] = t2; m3[pt] = t3;
        }
    }

    // publish all 4 per-quarter chains
    if (ln < 16) {
        #pragma unroll
        for (int pt = 0; pt < 4; ++pt) {
            mbuf[w][pt][lp][0] = m1[pt];
            mbuf[w][pt][lp][1] = m2[pt];
            mbuf[w][pt][lp][2] = m3[pt];
        }
    }
    __syncthreads();

    // ---- rescore: wave 0 -> positions 0-31 (pt 0,1), wave 1 -> 32-63 ----
    if (w < 2) {
        float lsum = 0.f;
        #pragma unroll
        for (int ptl = 0; ptl < 2; ++ptl) {
            const int pt = 2 * w + ptl;
            // merge the 4 quarters' chains (fixed order; unique top-3 set)
            float M1 = FMAX, M2 = FMAX, M3 = FMAX;
            #pragma unroll
            for (int ww = 0; ww < 4; ++ww)
                #pragma unroll
                for (int c = 0; c < 3; ++c) {
                    float u  = mbuf[ww][pt][lp][c];
                    float t3 = __builtin_amdgcn_fmed3f(M2, M3, u);
                    float t2 = __builtin_amdgcn_fmed3f(M1, M2, u);
                    M1 = fminf(M1, u); M2 = t2; M3 = t3;
                }
            int ks[3] = {(int)(__float_as_uint(M1) & 1023u),
                         (int)(__float_as_uint(M2) & 1023u),
                         (int)(__float_as_uint(M3) & 1023u)};

            // re-read this position's 32 channels (L1/L2-hot)
            float xr[32];
            const float* xgp = x + b * CHW + s0 + pt * 16 + lp;
            #pragma unroll
            for (int cs = 0; cs < 4; ++cs)
                #pragma unroll
                for (int j = 0; j < 8; ++j)
                    xr[cs * 8 + j] = xgp[(32 * cs + 8 * q + j) * HW];

            // exact fp32 rescore of the 3 candidates (same order as R4-R17)
            float dots[3];
            #pragma unroll
            for (int jj = 0; jj < 3; ++jj) {
                const float* crow = cb + ks[jj] * C_DIM + 8 * q;
                float p = 0.f;
                #pragma unroll
                for (int cs = 0; cs < 4; ++cs) {
                    float4 a0 = *(const float4*)(crow + 32 * cs);
                    float4 a1 = *(const float4*)(crow + 32 * cs + 4);
                    p = fmaf(xr[cs*8+0], a0.x, p); p = fmaf(xr[cs*8+1], a0.y, p);
                    p = fmaf(xr[cs*8+2], a0.z, p); p = fmaf(xr[cs*8+3], a0.w, p);
                    p = fmaf(xr[cs*8+4], a1.x, p); p = fmaf(xr[cs*8+5], a1.y, p);
                    p = fmaf(xr[cs*8+6], a1.z, p); p = fmaf(xr[cs*8+7], a1.w, p);
                }
                p += __shfl_xor(p, 16);
                p += __shfl_xor(p, 32);
                dots[jj] = p;
            }
            float sb = fmaf(r2v[pt], dots[0], c2w[ks[0]]); int kb = ks[0];
            float s2 = fmaf(r2v[pt], dots[1], c2w[ks[1]]);
            if (s2 < sb || (s2 == sb && ks[1] < kb)) { sb = s2; kb = ks[1]; }
            float s3 = fmaf(r2v[pt], dots[2], c2w[ks[2]]);
            if (s3 < sb || (s3 == sb && ks[2] < kb)) { sb = s3; kb = ks[2]; }

            if (ln < 16) {
                idxw[bid * 64 + pt * 16 + lp] = kb;
                ibuf[pt * 16 + lp] = kb;         // publish for fused store
            }
            lsum += sqrtf(fmaxf(1.0f + sb, 0.f));   // z2 == 1 after normalize
        }
        // each position counted by its 4 q-lanes -> scale 0.25
        #pragma unroll
        for (int off = 32; off > 0; off >>= 1) lsum += __shfl_down(lsum, off);
        if (ln == 0) atomicAdd(Sw, 0.25f * lsum);
    }

    // ---- fused q-store (b>0; batch 0's region aliases cbbf -> write_q0) ----
    __syncthreads();                             // ibuf visible to all waves
    if (b != 0) {
        const int row = ibuf[ln];                // position s0+ln's code
        const float4* cbr = (const float4*)cb + row * 32;
        float* ob = out + b * CHW + s0 + ln;
        #pragma unroll
        for (int c4 = w * 8; c4 < w * 8 + 8; ++c4) {   // wave w: 32 channels
            float4 v = cbr[c4];                  // 16B gather, L2-hot
            float* o = ob + (c4 * 4) * HW;
            o[0]      = v.x;                     // each store: 64 lanes x 4B
            o[HW]     = v.y;                     //  = coalesced 256B segment
            o[2 * HW] = v.z;
            o[3 * HW] = v.w;
        }
    }
}

// ---------------------------------------------------------------------------
// Kernel 3: batch-0 scatter (region was cbbf scratch during vq) + losses.
// ---------------------------------------------------------------------------
__global__ void write_q0(const float* __restrict__ cb,
                         const int* __restrict__ idxw,
                         const float* __restrict__ ws,
                         float* __restrict__ out) {
    int id = blockIdx.x * 256 + threadIdx.x;   // 131072 = 4096 * 32
    int s  = id & 4095;                        // spatial (lanes consecutive)
    int c4 = id >> 12;                         // channel quad 0..31
    int row = idxw[s];                         // batch 0 -> p == s
    float4 v = ((const float4*)cb)[row * 32 + c4];   // 16B gather, L2-hot
    float* o = out + (c4 * 4) * HW + s;        // b = 0
    o[0]      = v.x;
    o[HW]     = v.y;
    o[2 * HW] = v.z;
    o[3 * HW] = v.w;
    if (id == 0) {                             // loss finalize (after vq)
        float S = *(const float*)((const char*)ws + WS_S);
        float m = S / (float)N_POS;
        out[Q_ELEMS]     = 0.25f * m;
        out[Q_ELEMS + 1] = m;
    }
}

extern "C" void kernel_launch(void* const* d_in, const int* in_sizes, int n_in,
                              void* d_out, int out_size, void* d_ws, size_t ws_size,
                              hipStream_t stream) {
    const float* x  = (const float*)d_in[0];   // [16,128,64,64]
    const float* cb = (const float*)d_in[1];   // [1024,128]
    float* out = (float*)d_out;
    float* ws  = (float*)d_ws;

    const float* c2w = (const float*)((const char*)d_ws + WS_C2);
    int*  idxw = (int*)((char*)d_ws + WS_IDX);
    float* Sw  = (float*)((char*)d_ws + WS_S);
    unsigned short* cbbf = (unsigned short*)d_out;   // scratch in d_out

    prep_kernel<<<K_CODES, 64, 0, stream>>>(cb, ws, cbbf);
    vq_mfma    <<<N_POS / 64, 256, 0, stream>>>(x, cb, cbbf, c2w, idxw, Sw, out);
    write_q0   <<<512, 256, 0, stream>>>(cb, idxw, ws, out);
}

// Round 13
// 66.459 us; speedup vs baseline: 1.5156x; 1.0045x over previous
//
#include <hip/hip_runtime.h>
#include <math.h>

// Problem constants
#define K_CODES 1024
#define C_DIM   128
#define HW      4096          // 64*64
#define CHW     (C_DIM*HW)    // per-batch stride in x
#define N_POS   65536         // 16*64*64
#define Q_ELEMS 8388608       // 16*128*64*64

// ws layout (byte offsets).
#define WS_S    0             // float: sum of sqrt(d2min)
#define WS_C2   256           // float[1024]: ||c_k||^2
#define WS_IDX  8192          // int[65536]: final argmin index per position

// d_out scratch (overwritten later; stream-ordered, safe):
//   offset 0: bf16 codebook (256 KB), row k at k*256B, granule-col j holds
//   channels of granule (j ^ (k&7)) -> linear global_load_lds staging +
//   swizzled ds_read_b128 A-frags. This region == q's (b=0, c<16) slice,
//   so b=0 blocks skip the fused q-store (write_q0 covers batch 0 after).

typedef __attribute__((ext_vector_type(8))) short short8;   // 8 bf16 (4 VGPRs)
typedef __attribute__((ext_vector_type(4))) float f32x4;    // MFMA acc

__device__ __forceinline__ unsigned short f2bf(float f) {   // fp32 -> bf16 RNE
    unsigned u = __float_as_uint(f);
    u += 0x7FFFu + ((u >> 16) & 1u);
    return (unsigned short)(u >> 16);
}

// async global->LDS, 16B per lane; LDS dst = wave-uniform base (+lane*16 by HW)
__device__ __forceinline__ void gll16(const void* g, void* l) {
    __builtin_amdgcn_global_load_lds(
        (const __attribute__((address_space(1))) void*)g,
        (__attribute__((address_space(3))) void*)l, 16, 0, 0);
}

// ---------------------------------------------------------------------------
// Kernel 1: prep. R19: 256 blocks x 256 thr (4 waves), ONE code row per
// wave -- per-row math bit-identical to the 1024x64 version (same lane ->
// channel mapping, same shfl_down tree, same swizzled srow stores, same
// uint4 copy). 4x fewer blocks cuts the dispatch-dominated runtime.
// ---------------------------------------------------------------------------
__global__ __launch_bounds__(256) void prep_kernel(const float* __restrict__ cb,
                                                   float* __restrict__ ws,
                                                   unsigned short* __restrict__ cbbf) {
    __shared__ __align__(16) unsigned short srow[4][128];
    int t = threadIdx.x;
    int w = t >> 6;                            // wave -> row within block
    int l = t & 63;
    int k = blockIdx.x * 4 + w;                // code row
    if (blockIdx.x == 0 && t == 0) *(float*)((char*)ws + WS_S) = 0.f;
    float v1 = cb[k * C_DIM + l];
    float v2 = cb[k * C_DIM + 64 + l];
    int c1 = l, c2 = 64 + l;
    srow[w][(((c1 >> 3) ^ (k & 7)) << 3) | (c1 & 7)] = f2bf(v1);
    srow[w][(((c2 >> 3) ^ (k & 7)) << 3) | (c2 & 7)] = f2bf(v2);
    float ss = v1 * v1 + v2 * v2;
    #pragma unroll
    for (int off = 32; off > 0; off >>= 1) ss += __shfl_down(ss, off);
    if (l == 0) ((float*)((char*)ws + WS_C2))[k] = ss;
    __syncthreads();
    if (l < 16) ((uint4*)cbbf)[k * 16 + l] = ((const uint4*)srow[w])[l];
}

// ---------------------------------------------------------------------------
// Kernel 2: fused VQ. R19 = R18 (deduped x-prologue + wave-private barrier-
// free scan; session best 66.76 total, absmax 0.0) + HOISTED RESCORE LOADS:
// the w<2 waves issue their 64 xr reloads right BEFORE the mbuf barrier
// (values bit-identical -- x is read-only; only the issue point moves), so
// the L2/L3 latency hides under the barrier's wave-resync skew (waves are
// destaggered after the barrier-free scan) instead of being serially
// exposed in the tail. Everything else byte-identical to R18.
// ---------------------------------------------------------------------------
__global__ __launch_bounds__(256, 2) void vq_mfma(const float* __restrict__ x,
                                                  const float* __restrict__ cb,
                                                  const unsigned short* __restrict__ cbbf,
                                                  const float* __restrict__ c2w,
                                                  int* __restrict__ idxw,
                                                  float* __restrict__ Sw,
                                                  float* __restrict__ out) {
    __shared__ __align__(16) unsigned short cbuf[2][4][4096]; // 2 x 4 x 8 KB
    __shared__ float mbuf[4][4][16][3];                       // 3 KB
    __shared__ float nbuf[4][64];                             // 1 KB norms
    __shared__ int ibuf[64];                                  // 256 B

    const int t  = threadIdx.x;
    const int w  = t >> 6;                      // wave 0..3 = code quarter
    const int ln = t & 63;
    const int lp = ln & 15;                     // position lane (n index)
    const int q  = ln >> 4;                     // quad 0..3 (k sub-range)
    const int bid = blockIdx.x;
    const int b   = bid >> 6;                   // batch (64 blocks per image)
    const int s0  = (bid & 63) << 6;            // 64-position tile start

    // wave's quarter of the pre-swizzled bf16 codebook (64 KB)
    const char* gq = (const char*)cbbf + (w << 16);

    { // stage chunk 0 -> buf 0 NOW; latency hides under the x-prologue
        const char* gs = gq + (ln << 4);
        char* ld = (char*)&cbuf[0][w][0];
        #pragma unroll
        for (int r = 0; r < 8; ++r) gll16(gs + r * 1024, ld + r * 1024);
    }

    // ---- x-prologue: ONE coalesced load + convert per value, shared via
    //      LDS transpose buffer (aliases cbuf[1]; dead until chunk-1) ----
    unsigned short* xbuf = &cbuf[1][0][0];       // 64 pos x 128 ch bf16, 16 KB
    {
        float ssp = 0.f;
        const float* xgp = x + b * CHW + (w * 32) * HW + s0 + ln;
        #pragma unroll
        for (int g = 0; g < 4; ++g) {            // granule = 8 channels, 16B
            union { short8 v; unsigned short u[8]; } fu;
            #pragma unroll
            for (int j = 0; j < 8; ++j) {
                float vv = xgp[(g * 8 + j) * HW];   // 256B coalesced segment
                ssp = fmaf(vv, vv, ssp);
                fu.u[j] = f2bf(vv);
            }
            int col = (w * 4 + g) ^ (ln & 7);    // same swizzle family as cb
            *(short8*)(xbuf + ln * 128 + col * 8) = fu.v;
        }
        nbuf[w][ln] = ssp;                       // partial over w's 32 ch
    }
    __syncthreads();                             // xbuf + nbuf complete

    // norms: fixed pairwise order over the 4 wave-partials
    float r2v[4];
    #pragma unroll
    for (int pt = 0; pt < 4; ++pt) {
        const int pos = pt * 16 + lp;
        float s01 = nbuf[0][pos] + nbuf[1][pos];
        float s23 = nbuf[2][pos] + nbuf[3][pos];
        float s   = s01 + s23;
        r2v[pt] = -2.0f / fmaxf(sqrtf(s), 1e-12f);  // F.normalize eps
    }

    // fragments: identical layout/order as before (bit-identical bf16)
    short8 xf[4][4];
    #pragma unroll
    for (int pt = 0; pt < 4; ++pt)
        #pragma unroll
        for (int cs = 0; cs < 4; ++cs) {
            int col = (4 * cs + q) ^ (lp & 7);   // (pt*16+lp)&7 == lp&7
            xf[pt][cs] = *(const short8*)(xbuf + (pt * 16 + lp) * 128 + col * 8);
        }
    asm volatile("s_waitcnt lgkmcnt(0)" ::: "memory");  // xf live in regs
    __builtin_amdgcn_sched_barrier(0);
    __syncthreads();                             // xbuf free for chunk-1 staging

    const float FMAX = __uint_as_float(0x7F7FFFFFu);
    float m1[4] = {FMAX, FMAX, FMAX, FMAX};
    float m2[4] = {FMAX, FMAX, FMAX, FMAX};
    float m3[4] = {FMAX, FMAX, FMAX, FMAX};

    // chunk 0 landed (barrier drained vmcnt; belt-and-suspenders wave-local)
    asm volatile("s_waitcnt vmcnt(0)" ::: "memory");
    __builtin_amdgcn_sched_barrier(0);

    for (int i = 0; i < 8; ++i) {               // 8 chunks x 32 codes
        if (i < 7) {                             // stage next chunk (private)
            asm volatile("s_waitcnt lgkmcnt(0)" ::: "memory");
            const char* gs = gq + (i + 1) * 8192 + (ln << 4);
            char* ld = (char*)&cbuf[(i + 1) & 1][w][0];
            #pragma unroll
            for (int r = 0; r < 8; ++r) gll16(gs + r * 1024, ld + r * 1024);
        }

        const int k0 = (w << 8) + (i << 5);
        const unsigned short* cbp = &cbuf[i & 1][w][0];

        f32x4 acc[2][4];
        #pragma unroll
        for (int ct = 0; ct < 2; ++ct)
            #pragma unroll
            for (int pt = 0; pt < 4; ++pt) acc[ct][pt] = 0;

        #pragma unroll
        for (int cs = 0; cs < 4; ++cs) {
            short8 ah[2];
            #pragma unroll
            for (int ct = 0; ct < 2; ++ct) {     // A[m=16ct+lp][k=32cs+8q+j]
                int g = (16 * ct + lp) * 16 + ((4 * cs + q) ^ (lp & 7));
                ah[ct] = *(const short8*)(cbp + g * 8);
            }
            #pragma unroll
            for (int ct = 0; ct < 2; ++ct)
                #pragma unroll
                for (int pt = 0; pt < 4; ++pt)
                    acc[ct][pt] = __builtin_amdgcn_mfma_f32_16x16x32_bf16(
                        ah[ct], xf[pt][cs], acc[ct][pt], 0, 0, 0);
        }

        // ---- epilogue: 32 scores/lane (2ct x 4pt x 4reg) ----
        #pragma unroll
        for (int ct = 0; ct < 2; ++ct) {
            float4 c2vv = *(const float4*)(c2w + k0 + 16 * ct + 4 * q);
            float c2a[4] = {c2vv.x, c2vv.y, c2vv.z, c2vv.w};
            const int kb0 = k0 + 16 * ct + 4 * q;
            #pragma unroll
            for (int pt = 0; pt < 4; ++pt) {
                #pragma unroll
                for (int reg = 0; reg < 4; ++reg) {
                    float s = fmaf(r2v[pt], acc[ct][pt][reg], c2a[reg]);
                    unsigned pb = (__float_as_uint(s) & 0xFFFFFC00u) |
                                  (unsigned)(kb0 + reg);
                    float u  = __uint_as_float(pb);
                    float t3 = __builtin_amdgcn_fmed3f(m2[pt], m3[pt], u);
                    float t2 = __builtin_amdgcn_fmed3f(m1[pt], m2[pt], u);
                    m1[pt] = fminf(m1[pt], u); m2[pt] = t2; m3[pt] = t3;
                }
            }
        }

        if (i < 7) {                             // next chunk landed (wave-local)
            asm volatile("s_waitcnt vmcnt(0)" ::: "memory");
            __builtin_amdgcn_sched_barrier(0);
        }
    }

    // ---- merge chains across the 4 quad-lanes (butterfly, all 4 pt) ----
    #pragma unroll
    for (int d = 16; d <= 32; d <<= 1) {
        #pragma unroll
        for (int pt = 0; pt < 4; ++pt) {
            float o1 = __shfl_xor(m1[pt], d), o2 = __shfl_xor(m2[pt], d),
                  o3 = __shfl_xor(m3[pt], d);
            float u, t2, t3;
            u = o1; t3 = __builtin_amdgcn_fmed3f(m2[pt], m3[pt], u);
            t2 = __builtin_amdgcn_fmed3f(m1[pt], m2[pt], u);
            m1[pt] = fminf(m1[pt], u); m2[pt] = t2; m3[pt] = t3;
            u = o2; t3 = __builtin_amdgcn_fmed3f(m2[pt], m3[pt], u);
            t2 = __builtin_amdgcn_fmed3f(m1[pt], m2[pt], u);
            m1[pt] = fminf(m1[pt], u); m2[pt] = t2; m3[pt] = t3;
            u = o3; t3 = __builtin_amdgcn_fmed3f(m2[pt], m3[pt], u);
            t2 = __builtin_amdgcn_fmed3f(m1[pt], m2[pt], u);
            m1[pt] = fminf(m1[pt], u); m2[pt] = t2; m3[pt] = t3;
        }
    }

    // publish all 4 per-quarter chains
    if (ln < 16) {
        #pragma unroll
        for (int pt = 0; pt < 4; ++pt) {
            mbuf[w][pt][lp][0] = m1[pt];
            mbuf[w][pt][lp][1] = m2[pt];
            mbuf[w][pt][lp][2] = m3[pt];
        }
    }

    // ---- HOISTED rescore x-reload (bit-identical values; issued before the
    //      barrier so L2/L3 latency hides under the wave-resync skew) ----
    float xr2[2][32];
    if (w < 2) {
        #pragma unroll
        for (int ptl = 0; ptl < 2; ++ptl) {
            const int pt = 2 * w + ptl;
            const float* xgp = x + b * CHW + s0 + pt * 16 + lp;
            #pragma unroll
            for (int cs = 0; cs < 4; ++cs)
                #pragma unroll
                for (int j = 0; j < 8; ++j)
                    xr2[ptl][cs * 8 + j] = xgp[(32 * cs + 8 * q + j) * HW];
        }
    }
    __syncthreads();

    // ---- rescore: wave 0 -> positions 0-31 (pt 0,1), wave 1 -> 32-63 ----
    if (w < 2) {
        float lsum = 0.f;
        #pragma unroll
        for (int ptl = 0; ptl < 2; ++ptl) {
            const int pt = 2 * w + ptl;
            // merge the 4 quarters' chains (fixed order; unique top-3 set)
            float M1 = FMAX, M2 = FMAX, M3 = FMAX;
            #pragma unroll
            for (int ww = 0; ww < 4; ++ww)
                #pragma unroll
                for (int c = 0; c < 3; ++c) {
                    float u  = mbuf[ww][pt][lp][c];
                    float t3 = __builtin_amdgcn_fmed3f(M2, M3, u);
                    float t2 = __builtin_amdgcn_fmed3f(M1, M2, u);
                    M1 = fminf(M1, u); M2 = t2; M3 = t3;
                }
            int ks[3] = {(int)(__float_as_uint(M1) & 1023u),
                         (int)(__float_as_uint(M2) & 1023u),
                         (int)(__float_as_uint(M3) & 1023u)};

            const float* xr = xr2[ptl];          // preloaded, bit-identical

            // exact fp32 rescore of the 3 candidates (same order as R4-R18)
            float dots[3];
            #pragma unroll
            for (int jj = 0; jj < 3; ++jj) {
                const float* crow = cb + ks[jj] * C_DIM + 8 * q;
                float p = 0.f;
                #pragma unroll
                for (int cs = 0; cs < 4; ++cs) {
                    float4 a0 = *(const float4*)(crow + 32 * cs);
                    float4 a1 = *(const float4*)(crow + 32 * cs + 4);
                    p = fmaf(xr[cs*8+0], a0.x, p); p = fmaf(xr[cs*8+1], a0.y, p);
                    p = fmaf(xr[cs*8+2], a0.z, p); p = fmaf(xr[cs*8+3], a0.w, p);
                    p = fmaf(xr[cs*8+4], a1.x, p); p = fmaf(xr[cs*8+5], a1.y, p);
                    p = fmaf(xr[cs*8+6], a1.z, p); p = fmaf(xr[cs*8+7], a1.w, p);
                }
                p += __shfl_xor(p, 16);
                p += __shfl_xor(p, 32);
                dots[jj] = p;
            }
            float sb = fmaf(r2v[pt], dots[0], c2w[ks[0]]); int kb = ks[0];
            float s2 = fmaf(r2v[pt], dots[1], c2w[ks[1]]);
            if (s2 < sb || (s2 == sb && ks[1] < kb)) { sb = s2; kb = ks[1]; }
            float s3 = fmaf(r2v[pt], dots[2], c2w[ks[2]]);
            if (s3 < sb || (s3 == sb && ks[2] < kb)) { sb = s3; kb = ks[2]; }

            if (ln < 16) {
                idxw[bid * 64 + pt * 16 + lp] = kb;
                ibuf[pt * 16 + lp] = kb;         // publish for fused store
            }
            lsum += sqrtf(fmaxf(1.0f + sb, 0.f));   // z2 == 1 after normalize
        }
        // each position counted by its 4 q-lanes -> scale 0.25
        #pragma unroll
        for (int off = 32; off > 0; off >>= 1) lsum += __shfl_down(lsum, off);
        if (ln == 0) atomicAdd(Sw, 0.25f * lsum);
    }

    // ---- fused q-store (b>0; batch 0's region aliases cbbf -> write_q0) ----
    __syncthreads();                             // ibuf visible to all waves
    if (b != 0) {
        const int row = ibuf[ln];                // position s0+ln's code
        const float4* cbr = (const float4*)cb + row * 32;
        float* ob = out + b * CHW + s0 + ln;
        #pragma unroll
        for (int c4 = w * 8; c4 < w * 8 + 8; ++c4) {   // wave w: 32 channels
            float4 v = cbr[c4];                  // 16B gather, L2-hot
            float* o = ob + (c4 * 4) * HW;
            o[0]      = v.x;                     // each store: 64 lanes x 4B
            o[HW]     = v.y;                     //  = coalesced 256B segment
            o[2 * HW] = v.z;
            o[3 * HW] = v.w;
        }
    }
}

// ---------------------------------------------------------------------------
// Kernel 3: batch-0 scatter (region was cbbf scratch during vq) + losses.
// ---------------------------------------------------------------------------
__global__ void write_q0(const float* __restrict__ cb,
                         const int* __restrict__ idxw,
                         const float* __restrict__ ws,
                         float* __restrict__ out) {
    int id = blockIdx.x * 256 + threadIdx.x;   // 131072 = 4096 * 32
    int s  = id & 4095;                        // spatial (lanes consecutive)
    int c4 = id >> 12;                         // channel quad 0..31
    int row = idxw[s];                         // batch 0 -> p == s
    float4 v = ((const float4*)cb)[row * 32 + c4];   // 16B gather, L2-hot
    float* o = out + (c4 * 4) * HW + s;        // b = 0
    o[0]      = v.x;
    o[HW]     = v.y;
    o[2 * HW] = v.z;
    o[3 * HW] = v.w;
    if (id == 0) {                             // loss finalize (after vq)
        float S = *(const float*)((const char*)ws + WS_S);
        float m = S / (float)N_POS;
        out[Q_ELEMS]     = 0.25f * m;
        out[Q_ELEMS + 1] = m;
    }
}

extern "C" void kernel_launch(void* const* d_in, const int* in_sizes, int n_in,
                              void* d_out, int out_size, void* d_ws, size_t ws_size,
                              hipStream_t stream) {
    const float* x  = (const float*)d_in[0];   // [16,128,64,64]
    const float* cb = (const float*)d_in[1];   // [1024,128]
    float* out = (float*)d_out;
    float* ws  = (float*)d_ws;

    const float* c2w = (const float*)((const char*)d_ws + WS_C2);
    int*  idxw = (int*)((char*)d_ws + WS_IDX);
    float* Sw  = (float*)((char*)d_ws + WS_S);
    unsigned short* cbbf = (unsigned short*)d_out;   // scratch in d_out

    prep_kernel<<<K_CODES / 4, 256, 0, stream>>>(cb, ws, cbbf);
    vq_mfma    <<<N_POS / 64, 256, 0, stream>>>(x, cb, cbbf, c2w, idxw, Sw, out);
    write_q0   <<<512, 256, 0, stream>>>(cb, idxw, ws, out);
}

// Round 14
// 65.151 us; speedup vs baseline: 1.5461x; 1.0201x over previous
//
#include <hip/hip_runtime.h>
#include <math.h>

// Problem constants
#define K_CODES 1024
#define C_DIM   128
#define HW      4096          // 64*64
#define CHW     (C_DIM*HW)    // per-batch stride in x
#define N_POS   65536         // 16*64*64
#define Q_ELEMS 8388608       // 16*128*64*64

// ws layout (byte offsets).
#define WS_S    0             // float: sum of sqrt(d2min)
#define WS_C2   256           // float[1024]: ||c_k||^2
#define WS_IDX  8192          // int[65536]: final argmin index per position

// d_out scratch (overwritten later; stream-ordered, safe):
//   offset 0: bf16 codebook (256 KB), row k at k*256B, granule-col j holds
//   channels of granule (j ^ (k&7)) -> linear global_load_lds staging +
//   swizzled ds_read_b128 A-frags. This region == q's (b=0, c<16) slice,
//   so b=0 blocks skip the fused q-store (write_q0 covers batch 0 after).

typedef __attribute__((ext_vector_type(8))) short short8;   // 8 bf16 (4 VGPRs)
typedef __attribute__((ext_vector_type(4))) float f32x4;    // MFMA acc

__device__ __forceinline__ unsigned short f2bf(float f) {   // fp32 -> bf16 RNE
    unsigned u = __float_as_uint(f);
    u += 0x7FFFu + ((u >> 16) & 1u);
    return (unsigned short)(u >> 16);
}

// async global->LDS, 16B per lane; LDS dst = wave-uniform base (+lane*16 by HW)
__device__ __forceinline__ void gll16(const void* g, void* l) {
    __builtin_amdgcn_global_load_lds(
        (const __attribute__((address_space(1))) void*)g,
        (__attribute__((address_space(3))) void*)l, 16, 0, 0);
}

// ---------------------------------------------------------------------------
// Kernel 1: prep. 256 blocks x 256 thr (4 waves), one code row per wave --
// per-row math bit-identical to the original 1024x64 version. (R19)
// ---------------------------------------------------------------------------
__global__ __launch_bounds__(256) void prep_kernel(const float* __restrict__ cb,
                                                   float* __restrict__ ws,
                                                   unsigned short* __restrict__ cbbf) {
    __shared__ __align__(16) unsigned short srow[4][128];
    int t = threadIdx.x;
    int w = t >> 6;                            // wave -> row within block
    int l = t & 63;
    int k = blockIdx.x * 4 + w;                // code row
    if (blockIdx.x == 0 && t == 0) *(float*)((char*)ws + WS_S) = 0.f;
    float v1 = cb[k * C_DIM + l];
    float v2 = cb[k * C_DIM + 64 + l];
    int c1 = l, c2 = 64 + l;
    srow[w][(((c1 >> 3) ^ (k & 7)) << 3) | (c1 & 7)] = f2bf(v1);
    srow[w][(((c2 >> 3) ^ (k & 7)) << 3) | (c2 & 7)] = f2bf(v2);
    float ss = v1 * v1 + v2 * v2;
    #pragma unroll
    for (int off = 32; off > 0; off >>= 1) ss += __shfl_down(ss, off);
    if (l == 0) ((float*)((char*)ws + WS_C2))[k] = ss;
    __syncthreads();
    if (l < 16) ((uint4*)cbbf)[k * 16 + l] = ((const uint4*)srow[w])[l];
}

// ---------------------------------------------------------------------------
// Kernel 2: fused VQ. R20 = R19 (deduped x-prologue, wave-private scan,
// hoisted rescore, fused q-store; 66.46 total, absmax 0.0) with the scan
// re-pipelined as a COUNTED-VMCNT 2-DEEP PIPELINE (T4):
//  - 16-code chunks (4 KB/wave; epilogue math byte-identical to R14, which
//    was absmax-verified), 3-buffer rotation, stage chunk i+2 at top of
//    iter i -> ~1.5 chunk-periods of staging lead.
//  - the per-chunk c2 float4 VMEM load is issued FIRST in the iteration, so
//    the compiler's c2-use wait (in-order vmcnt) retires ch_{i+1} but leaves
//    ch_{i+2} in flight; explicit gates are COUNTED -- vmcnt(9)/(5)/(1),
//    never 0 -> no full VMEM drain anywhere in the loop (R13-R19 drained
//    every chunk via the c2 wait; that was the hidden serializer).
//  - LDS 70.1 -> ~53.8 KB -> 3 blocks/CU co-resident possible (12 waves/CU).
// vmcnt gate proof: at iter i's gate there are >=9 loads newer than chunk
// i's 4 (ch_{i+1}:4, c2_i:1, ch_{i+2}:4); in-order retirement => "<=9
// outstanding" implies chunk i landed. Tail: i=14 -> 5 newer, i=15 -> 1.
// ---------------------------------------------------------------------------
__global__ __launch_bounds__(256, 2) void vq_mfma(const float* __restrict__ x,
                                                  const float* __restrict__ cb,
                                                  const unsigned short* __restrict__ cbbf,
                                                  const float* __restrict__ c2w,
                                                  int* __restrict__ idxw,
                                                  float* __restrict__ Sw,
                                                  float* __restrict__ out) {
    __shared__ __align__(16) unsigned short cbuf[3][4][2048]; // 3 x 16 KB
    __shared__ float mbuf[4][4][16][3];                       // 3 KB
    __shared__ float nbuf[4][64];                             // 1 KB norms
    __shared__ int ibuf[64];                                  // 256 B

    const int t  = threadIdx.x;
    const int w  = t >> 6;                      // wave 0..3 = code quarter
    const int ln = t & 63;
    const int lp = ln & 15;                     // position lane (n index)
    const int q  = ln >> 4;                     // quad 0..3 (k sub-range)
    const int bid = blockIdx.x;
    const int b   = bid >> 6;                   // batch (64 blocks per image)
    const int s0  = (bid & 63) << 6;            // 64-position tile start

    // wave's quarter of the pre-swizzled bf16 codebook (64 KB)
    const char* gq = (const char*)cbbf + (w << 16);

    { // stage chunks 0,1 -> buffers 0,1 NOW; latency hides under x-prologue
        const char* gs = gq + (ln << 4);
        char* l0 = (char*)&cbuf[0][w][0];
        char* l1 = (char*)&cbuf[1][w][0];
        #pragma unroll
        for (int r = 0; r < 4; ++r) gll16(gs + r * 1024, l0 + r * 1024);
        #pragma unroll
        for (int r = 0; r < 4; ++r) gll16(gs + 4096 + r * 1024, l1 + r * 1024);
    }

    // ---- x-prologue: ONE coalesced load + convert per value, shared via
    //      LDS transpose buffer (aliases cbuf[2]; dead until chunk-2) ----
    unsigned short* xbuf = &cbuf[2][0][0];       // 64 pos x 128 ch bf16, 16 KB
    {
        float ssp = 0.f;
        const float* xgp = x + b * CHW + (w * 32) * HW + s0 + ln;
        #pragma unroll
        for (int g = 0; g < 4; ++g) {            // granule = 8 channels, 16B
            union { short8 v; unsigned short u[8]; } fu;
            #pragma unroll
            for (int j = 0; j < 8; ++j) {
                float vv = xgp[(g * 8 + j) * HW];   // 256B coalesced segment
                ssp = fmaf(vv, vv, ssp);
                fu.u[j] = f2bf(vv);
            }
            int col = (w * 4 + g) ^ (ln & 7);    // same swizzle family as cb
            *(short8*)(xbuf + ln * 128 + col * 8) = fu.v;
        }
        nbuf[w][ln] = ssp;                       // partial over w's 32 ch
    }
    __syncthreads();                             // xbuf + nbuf complete

    // norms: fixed pairwise order over the 4 wave-partials
    float r2v[4];
    #pragma unroll
    for (int pt = 0; pt < 4; ++pt) {
        const int pos = pt * 16 + lp;
        float s01 = nbuf[0][pos] + nbuf[1][pos];
        float s23 = nbuf[2][pos] + nbuf[3][pos];
        float s   = s01 + s23;
        r2v[pt] = -2.0f / fmaxf(sqrtf(s), 1e-12f);  // F.normalize eps
    }

    // fragments: identical layout/order (bit-identical bf16)
    short8 xf[4][4];
    #pragma unroll
    for (int pt = 0; pt < 4; ++pt)
        #pragma unroll
        for (int cs = 0; cs < 4; ++cs) {
            int col = (4 * cs + q) ^ (lp & 7);   // (pt*16+lp)&7 == lp&7
            xf[pt][cs] = *(const short8*)(xbuf + (pt * 16 + lp) * 128 + col * 8);
        }
    asm volatile("s_waitcnt lgkmcnt(0)" ::: "memory");  // xf live in regs
    __builtin_amdgcn_sched_barrier(0);
    __syncthreads();                             // xbuf (buf 2) free for ch2

    const float FMAX = __uint_as_float(0x7F7FFFFFu);
    float m1[4] = {FMAX, FMAX, FMAX, FMAX};
    float m2[4] = {FMAX, FMAX, FMAX, FMAX};
    float m3[4] = {FMAX, FMAX, FMAX, FMAX};

    for (int i = 0; i < 16; ++i) {              // 16 chunks x 16 codes
        const int k0 = (w << 8) + (i << 4);
        // c2 first: its compiler-inserted wait retires ch_{i+1} (older) but
        // leaves ch_{i+2} (newer) in flight -- no full drain.
        float4 c2vv = *(const float4*)(c2w + k0 + 4 * q);

        if (i < 14) {                            // stage chunk i+2 (private)
            asm volatile("s_waitcnt lgkmcnt(0)" ::: "memory");
            const char* gs = gq + (i + 2) * 4096 + (ln << 4);
            char* ld = (char*)&cbuf[(i + 2) % 3][w][0];
            #pragma unroll
            for (int r = 0; r < 4; ++r) gll16(gs + r * 1024, ld + r * 1024);
        }

        // counted gate: chunk i landed; ch_{i+1}/c2/ch_{i+2} stay in flight
        if (i < 14)       asm volatile("s_waitcnt vmcnt(9)" ::: "memory");
        else if (i == 14) asm volatile("s_waitcnt vmcnt(5)" ::: "memory");
        else              asm volatile("s_waitcnt vmcnt(1)" ::: "memory");
        __builtin_amdgcn_sched_barrier(0);

        const unsigned short* cbp = &cbuf[i % 3][w][0];

        f32x4 acc[4];
        #pragma unroll
        for (int pt = 0; pt < 4; ++pt) acc[pt] = 0;

        #pragma unroll
        for (int cs = 0; cs < 4; ++cs) {
            // A[m=lp][k=32cs+8q+j]; row-within-chunk = lp, swizzled granule
            int g = lp * 16 + ((4 * cs + q) ^ (lp & 7));
            short8 ah = *(const short8*)(cbp + g * 8);
            #pragma unroll
            for (int pt = 0; pt < 4; ++pt)
                acc[pt] = __builtin_amdgcn_mfma_f32_16x16x32_bf16(
                    ah, xf[pt][cs], acc[pt], 0, 0, 0);
        }

        // ---- epilogue: 16 scores/lane (4pt x 4reg) -- R14-verified math ----
        {
            float c2a[4] = {c2vv.x, c2vv.y, c2vv.z, c2vv.w};
            const int kb0 = k0 + 4 * q;
            #pragma unroll
            for (int pt = 0; pt < 4; ++pt) {
                #pragma unroll
                for (int reg = 0; reg < 4; ++reg) {
                    float s = fmaf(r2v[pt], acc[pt][reg], c2a[reg]);
                    unsigned pb = (__float_as_uint(s) & 0xFFFFFC00u) |
                                  (unsigned)(kb0 + reg);
                    float u  = __uint_as_float(pb);
                    float t3 = __builtin_amdgcn_fmed3f(m2[pt], m3[pt], u);
                    float t2 = __builtin_amdgcn_fmed3f(m1[pt], m2[pt], u);
                    m1[pt] = fminf(m1[pt], u); m2[pt] = t2; m3[pt] = t3;
                }
            }
        }
    }

    // ---- merge chains across the 4 quad-lanes (butterfly, all 4 pt) ----
    #pragma unroll
    for (int d = 16; d <= 32; d <<= 1) {
        #pragma unroll
        for (int pt = 0; pt < 4; ++pt) {
            float o1 = __shfl_xor(m1[pt], d), o2 = __shfl_xor(m2[pt], d),
                  o3 = __shfl_xor(m3[pt], d);
            float u, t2, t3;
            u = o1; t3 = __builtin_amdgcn_fmed3f(m2[pt], m3[pt], u);
            t2 = __builtin_amdgcn_fmed3f(m1[pt], m2[pt], u);
            m1[pt] = fminf(m1[pt], u); m2[pt] = t2; m3[pt] = t3;
            u = o2; t3 = __builtin_amdgcn_fmed3f(m2[pt], m3[pt], u);
            t2 = __builtin_amdgcn_fmed3f(m1[pt], m2[pt], u);
            m1[pt] = fminf(m1[pt], u); m2[pt] = t2; m3[pt] = t3;
            u = o3; t3 = __builtin_amdgcn_fmed3f(m2[pt], m3[pt], u);
            t2 = __builtin_amdgcn_fmed3f(m1[pt], m2[pt], u);
            m1[pt] = fminf(m1[pt], u); m2[pt] = t2; m3[pt] = t3;
        }
    }

    // publish all 4 per-quarter chains
    if (ln < 16) {
        #pragma unroll
        for (int pt = 0; pt < 4; ++pt) {
            mbuf[w][pt][lp][0] = m1[pt];
            mbuf[w][pt][lp][1] = m2[pt];
            mbuf[w][pt][lp][2] = m3[pt];
        }
    }

    // ---- hoisted rescore x-reload (bit-identical; hides under barrier) ----
    float xr2[2][32];
    if (w < 2) {
        #pragma unroll
        for (int ptl = 0; ptl < 2; ++ptl) {
            const int pt = 2 * w + ptl;
            const float* xgp = x + b * CHW + s0 + pt * 16 + lp;
            #pragma unroll
            for (int cs = 0; cs < 4; ++cs)
                #pragma unroll
                for (int j = 0; j < 8; ++j)
                    xr2[ptl][cs * 8 + j] = xgp[(32 * cs + 8 * q + j) * HW];
        }
    }
    __syncthreads();

    // ---- rescore: wave 0 -> positions 0-31 (pt 0,1), wave 1 -> 32-63 ----
    if (w < 2) {
        float lsum = 0.f;
        #pragma unroll
        for (int ptl = 0; ptl < 2; ++ptl) {
            const int pt = 2 * w + ptl;
            // merge the 4 quarters' chains (fixed order; unique top-3 set)
            float M1 = FMAX, M2 = FMAX, M3 = FMAX;
            #pragma unroll
            for (int ww = 0; ww < 4; ++ww)
                #pragma unroll
                for (int c = 0; c < 3; ++c) {
                    float u  = mbuf[ww][pt][lp][c];
                    float t3 = __builtin_amdgcn_fmed3f(M2, M3, u);
                    float t2 = __builtin_amdgcn_fmed3f(M1, M2, u);
                    M1 = fminf(M1, u); M2 = t2; M3 = t3;
                }
            int ks[3] = {(int)(__float_as_uint(M1) & 1023u),
                         (int)(__float_as_uint(M2) & 1023u),
                         (int)(__float_as_uint(M3) & 1023u)};

            const float* xr = xr2[ptl];          // preloaded, bit-identical

            // exact fp32 rescore of the 3 candidates (same order as R4-R19)
            float dots[3];
            #pragma unroll
            for (int jj = 0; jj < 3; ++jj) {
                const float* crow = cb + ks[jj] * C_DIM + 8 * q;
                float p = 0.f;
                #pragma unroll
                for (int cs = 0; cs < 4; ++cs) {
                    float4 a0 = *(const float4*)(crow + 32 * cs);
                    float4 a1 = *(const float4*)(crow + 32 * cs + 4);
                    p = fmaf(xr[cs*8+0], a0.x, p); p = fmaf(xr[cs*8+1], a0.y, p);
                    p = fmaf(xr[cs*8+2], a0.z, p); p = fmaf(xr[cs*8+3], a0.w, p);
                    p = fmaf(xr[cs*8+4], a1.x, p); p = fmaf(xr[cs*8+5], a1.y, p);
                    p = fmaf(xr[cs*8+6], a1.z, p); p = fmaf(xr[cs*8+7], a1.w, p);
                }
                p += __shfl_xor(p, 16);
                p += __shfl_xor(p, 32);
                dots[jj] = p;
            }
            float sb = fmaf(r2v[pt], dots[0], c2w[ks[0]]); int kb = ks[0];
            float s2 = fmaf(r2v[pt], dots[1], c2w[ks[1]]);
            if (s2 < sb || (s2 == sb && ks[1] < kb)) { sb = s2; kb = ks[1]; }
            float s3 = fmaf(r2v[pt], dots[2], c2w[ks[2]]);
            if (s3 < sb || (s3 == sb && ks[2] < kb)) { sb = s3; kb = ks[2]; }

            if (ln < 16) {
                idxw[bid * 64 + pt * 16 + lp] = kb;
                ibuf[pt * 16 + lp] = kb;         // publish for fused store
            }
            lsum += sqrtf(fmaxf(1.0f + sb, 0.f));   // z2 == 1 after normalize
        }
        // each position counted by its 4 q-lanes -> scale 0.25
        #pragma unroll
        for (int off = 32; off > 0; off >>= 1) lsum += __shfl_down(lsum, off);
        if (ln == 0) atomicAdd(Sw, 0.25f * lsum);
    }

    // ---- fused q-store (b>0; batch 0's region aliases cbbf -> write_q0) ----
    __syncthreads();                             // ibuf visible to all waves
    if (b != 0) {
        const int row = ibuf[ln];                // position s0+ln's code
        const float4* cbr = (const float4*)cb + row * 32;
        float* ob = out + b * CHW + s0 + ln;
        #pragma unroll
        for (int c4 = w * 8; c4 < w * 8 + 8; ++c4) {   // wave w: 32 channels
            float4 v = cbr[c4];                  // 16B gather, L2-hot
            float* o = ob + (c4 * 4) * HW;
            o[0]      = v.x;                     // each store: 64 lanes x 4B
            o[HW]     = v.y;                     //  = coalesced 256B segment
            o[2 * HW] = v.z;
            o[3 * HW] = v.w;
        }
    }
}

// ---------------------------------------------------------------------------
// Kernel 3: batch-0 scatter (region was cbbf scratch during vq) + losses.
// ---------------------------------------------------------------------------
__global__ void write_q0(const float* __restrict__ cb,
                         const int* __restrict__ idxw,
                         const float* __restrict__ ws,
                         float* __restrict__ out) {
    int id = blockIdx.x * 256 + threadIdx.x;   // 131072 = 4096 * 32
    int s  = id & 4095;                        // spatial (lanes consecutive)
    int c4 = id >> 12;                         // channel quad 0..31
    int row = idxw[s];                         // batch 0 -> p == s
    float4 v = ((const float4*)cb)[row * 32 + c4];   // 16B gather, L2-hot
    float* o = out + (c4 * 4) * HW + s;        // b = 0
    o[0]      = v.x;
    o[HW]     = v.y;
    o[2 * HW] = v.z;
    o[3 * HW] = v.w;
    if (id == 0) {                             // loss finalize (after vq)
        float S = *(const float*)((const char*)ws + WS_S);
        float m = S / (float)N_POS;
        out[Q_ELEMS]     = 0.25f * m;
        out[Q_ELEMS + 1] = m;
    }
}

extern "C" void kernel_launch(void* const* d_in, const int* in_sizes, int n_in,
                              void* d_out, int out_size, void* d_ws, size_t ws_size,
                              hipStream_t stream) {
    const float* x  = (const float*)d_in[0];   // [16,128,64,64]
    const float* cb = (const float*)d_in[1];   // [1024,128]
    float* out = (float*)d_out;
    float* ws  = (float*)d_ws;

    const float* c2w = (const float*)((const char*)d_ws + WS_C2);
    int*  idxw = (int*)((char*)d_ws + WS_IDX);
    float* Sw  = (float*)((char*)d_ws + WS_S);
    unsigned short* cbbf = (unsigned short*)d_out;   // scratch in d_out

    prep_kernel<<<K_CODES / 4, 256, 0, stream>>>(cb, ws, cbbf);
    vq_mfma    <<<N_POS / 64, 256, 0, stream>>>(x, cb, cbbf, c2w, idxw, Sw, out);
    write_q0   <<<512, 256, 0, stream>>>(cb, idxw, ws, out);
}